// Round 3
// baseline (1576.523 us; speedup 1.0000x reference)
//
#include <hip/hip_runtime.h>
#include <hip/hip_bf16.h>
#include <stdint.h>

using bf16 = __hip_bfloat16;
using bf16x8 = __attribute__((ext_vector_type(8))) __bf16;
using f32x4  = __attribute__((ext_vector_type(4))) float;

#define NTOK 2048
#define DIM 1024
#define NH 16
#define NKV 4
#define HDIM 64
#define NE 8
#define NF 2048
#define SEQ 1024
#define MAXR 5120      // 4096 pairs + 8*128 alignment slack
#define MAXTILES 40

__device__ __forceinline__ float b2f(unsigned short u){ unsigned v=((unsigned)u)<<16; float f; __builtin_memcpy(&f,&v,4); return f; }
__device__ __forceinline__ unsigned short f2b(float f){ bf16 h=__float2bfloat16(f); unsigned short u; __builtin_memcpy(&u,&h,2); return u; }

// ---------------- zero small int buffers ----------------
__global__ void k_zero_i32(int* p, int n){ int i=blockIdx.x*256+threadIdx.x; if(i<n) p[i]=0; }

// ---------------- transpose+cast: fp32 [Z][R][C] -> bf16 [Z][C][R] ----------------
__global__ __launch_bounds__(256) void k_transpose(const float* __restrict__ in, bf16* __restrict__ out, int R, int C){
  __shared__ float tile[32][33];
  int bx = blockIdx.x*32, by = blockIdx.y*32;
  size_t base = (size_t)blockIdx.z * R * C;
  int x = threadIdx.x, y0 = threadIdx.y;
  const float* src = in + base;
  bf16* dst = out + base;
#pragma unroll
  for (int i=0;i<4;i++){ int r = y0 + i*8; tile[r][x] = src[(size_t)(by+r)*C + bx + x]; }
  __syncthreads();
#pragma unroll
  for (int i=0;i<4;i++){ int c = y0 + i*8; dst[(size_t)(bx+c)*R + by + x] = __float2bfloat16(tile[x][c]); }
}

// ---------------- RMSNorm fp32 -> bf16 ----------------
__global__ __launch_bounds__(256) void k_rmsnorm(const float* __restrict__ x, const float* __restrict__ w, bf16* __restrict__ out){
  int row = blockIdx.x, t = threadIdx.x;
  const float4 v = ((const float4*)(x + (size_t)row*DIM))[t];
  float ss = v.x*v.x + v.y*v.y + v.z*v.z + v.w*v.w;
#pragma unroll
  for (int m=1;m<64;m<<=1) ss += __shfl_xor(ss, m);
  __shared__ float red[4];
  if ((t&63)==0) red[t>>6] = ss;
  __syncthreads();
  float tot = red[0]+red[1]+red[2]+red[3];
  float r = rsqrtf(tot * (1.0f/DIM) + 1e-6f);
  const float4 wv = ((const float4*)w)[t];
  ushort4 o;
  o.x = f2b(v.x*r*wv.x); o.y = f2b(v.y*r*wv.y); o.z = f2b(v.z*r*wv.z); o.w = f2b(v.w*r*wv.w);
  ((ushort4*)(out + (size_t)row*DIM))[t] = o;
}

// ---------------- MFMA GEMM: A[M x K] row-major, Bt[N x K] row-major ----------------
// MODE 0: C bf16            MODE 1: C fp32 = acc + resid
// MODE 2: per-expert B (tile map), C bf16
// MODE 3: per-expert B (tile map), scatter to ybuf[slot][tok][col] = acc*w
#define BM 128
#define BN 128
#define BK 32

template<int MODE>
__global__ __launch_bounds__(256) void k_gemm(
    const bf16* __restrict__ A, const bf16* __restrict__ Bt,
    bf16* __restrict__ Cb, float* __restrict__ Cf, const float* __restrict__ resid,
    const int* __restrict__ tile_expert, const int* __restrict__ row_tok,
    const float* __restrict__ row_w, const int* __restrict__ row_slot,
    int N, int K)
{
  int tn = blockIdx.x, tm = blockIdx.y;
  int e = 0;
  if constexpr (MODE >= 2){ e = tile_expert[tm]; if (e < 0) return; }
  const bf16* Ablk = A + (size_t)tm*BM*K;
  const bf16* Bblk = Bt + ((MODE>=2) ? (size_t)e*N*K : (size_t)0) + (size_t)tn*BN*K;

  __shared__ bf16 lA[BM*BK];
  __shared__ bf16 lB[BN*BK];

  int t = threadIdx.x;
  int lane = t & 63, wave = t >> 6;
  int wr = wave >> 1, wc = wave & 1;
  int lr = lane & 15, lg = lane >> 4;

  int sr = t >> 2;        // staging row within 64-row chunk
  int sk = (t & 3) * 8;   // staging k offset

  f32x4 acc[4][4] = {};

  for (int k0 = 0; k0 < K; k0 += BK){
    bf16x8 va0 = *(const bf16x8*)(Ablk + (size_t)sr*K + k0 + sk);
    bf16x8 va1 = *(const bf16x8*)(Ablk + (size_t)(64+sr)*K + k0 + sk);
    bf16x8 vb0 = *(const bf16x8*)(Bblk + (size_t)sr*K + k0 + sk);
    bf16x8 vb1 = *(const bf16x8*)(Bblk + (size_t)(64+sr)*K + k0 + sk);
    __syncthreads();
    *(bf16x8*)(lA + t*8) = va0;
    *(bf16x8*)(lA + 2048 + t*8) = va1;
    *(bf16x8*)(lB + t*8) = vb0;
    *(bf16x8*)(lB + 2048 + t*8) = vb1;
    __syncthreads();
    bf16x8 af[4], bfv[4];
#pragma unroll
    for (int m=0;m<4;m++) af[m]  = *(const bf16x8*)(lA + (wr*64 + m*16 + lr)*BK + lg*8);
#pragma unroll
    for (int n=0;n<4;n++) bfv[n] = *(const bf16x8*)(lB + (wc*64 + n*16 + lr)*BK + lg*8);
#pragma unroll
    for (int m=0;m<4;m++)
#pragma unroll
      for (int n=0;n<4;n++)
        acc[m][n] = __builtin_amdgcn_mfma_f32_16x16x32_bf16(af[m], bfv[n], acc[m][n], 0, 0, 0);
  }

#pragma unroll
  for (int m=0;m<4;m++){
#pragma unroll
    for (int n=0;n<4;n++){
      int col = tn*BN + wc*64 + n*16 + lr;
#pragma unroll
      for (int j=0;j<4;j++){
        int row = tm*BM + wr*64 + m*16 + lg*4 + j;
        float v = acc[m][n][j];
        if constexpr (MODE==0 || MODE==2){
          Cb[(size_t)row*N + col] = __float2bfloat16(v);
        } else if constexpr (MODE==1){
          Cf[(size_t)row*N + col] = v + resid[(size_t)row*N + col];
        } else {
          int tok = row_tok[row];
          if (tok >= 0) Cf[((size_t)row_slot[row]*NTOK + tok)*DIM + col] = v * row_w[row];
        }
      }
    }
  }
}

// ---------------- RoPE + reshape qkv[T][1536] -> qr[B,H,S,HD], kr/vr[B,KV,S,HD] ----------------
__global__ __launch_bounds__(64) void k_rope(const bf16* __restrict__ qkv, const int* __restrict__ pos_ids,
    bf16* __restrict__ qr, bf16* __restrict__ kr, bf16* __restrict__ vr){
  int tk = blockIdx.x;
  int b = tk >> 10, s = tk & 1023;
  int d = threadIdx.x;
  float p = (float)pos_ids[tk];
  int i = d & 31;
  float freq = p * powf(10000.0f, -(float)(2*i)*(1.0f/HDIM));
  float sn, cs;
  sincosf(freq, &sn, &cs);
  const bf16* row = qkv + (size_t)tk*1536;
#pragma unroll
  for (int h=0; h<NH; h++){
    float x  = __bfloat162float(row[h*64 + d]);
    float xp = __bfloat162float(row[h*64 + ((d+32)&63)]);
    float rh = (d<32) ? -xp : xp;
    qr[(((size_t)(b*NH+h)*SEQ)+s)*HDIM + d] = __float2bfloat16(x*cs + rh*sn);
  }
#pragma unroll
  for (int h=0; h<NKV; h++){
    float x  = __bfloat162float(row[1024 + h*64 + d]);
    float xp = __bfloat162float(row[1024 + h*64 + ((d+32)&63)]);
    float rh = (d<32) ? -xp : xp;
    kr[(((size_t)(b*NKV+h)*SEQ)+s)*HDIM + d] = __float2bfloat16(x*cs + rh*sn);
    vr[(((size_t)(b*NKV+h)*SEQ)+s)*HDIM + d] = row[1280 + h*64 + d];
  }
}

// ---------------- causal attention, 1 wave per (b,h,q) row, online softmax ----------------
__global__ __launch_bounds__(64) void k_attn(const bf16* __restrict__ qr, const bf16* __restrict__ kr,
    const bf16* __restrict__ vr, bf16* __restrict__ out){
  int q = blockIdx.x, h = blockIdx.y, b = blockIdx.z;
  int lane = threadIdx.x;
  int kv = h >> 2;
  const unsigned short* Q  = (const unsigned short*)(qr + (((size_t)(b*NH+h)*SEQ) + q)*HDIM);
  const unsigned short* Kb = (const unsigned short*)(kr + ((size_t)(b*NKV+kv)*SEQ)*HDIM);
  const unsigned short* Vb = (const unsigned short*)(vr + ((size_t)(b*NKV+kv)*SEQ)*HDIM);
  __shared__ float lq[64];
  lq[lane] = b2f(Q[lane]);
  __syncthreads();
  float qv[64];
#pragma unroll
  for (int i=0;i<64;i++) qv[i] = lq[i];
  float m = -1e30f, l = 0.f, oa = 0.f;
  for (int kt=0; kt<=q; kt+=64){
    int k = kt + lane;
    float s = -1e30f;
    if (k <= q){
      const uint4* K4 = (const uint4*)(Kb + (size_t)k*HDIM);
      float dot = 0.f;
#pragma unroll
      for (int c=0;c<8;c++){
        uint4 u = K4[c];
        dot += qv[c*8+0]*b2f((unsigned short)(u.x&0xffff));
        dot += qv[c*8+1]*b2f((unsigned short)(u.x>>16));
        dot += qv[c*8+2]*b2f((unsigned short)(u.y&0xffff));
        dot += qv[c*8+3]*b2f((unsigned short)(u.y>>16));
        dot += qv[c*8+4]*b2f((unsigned short)(u.z&0xffff));
        dot += qv[c*8+5]*b2f((unsigned short)(u.z>>16));
        dot += qv[c*8+6]*b2f((unsigned short)(u.w&0xffff));
        dot += qv[c*8+7]*b2f((unsigned short)(u.w>>16));
      }
      s = dot * 0.125f;
    }
    float cm = s;
#pragma unroll
    for (int mm=1;mm<64;mm<<=1) cm = fmaxf(cm, __shfl_xor(cm, mm));
    float mn = fmaxf(m, cm);
    float corr = __expf(m - mn);
    float pp = __expf(s - mn);
    float ps = pp;
#pragma unroll
    for (int mm=1;mm<64;mm<<=1) ps += __shfl_xor(ps, mm);
    l = l*corr + ps;
    oa *= corr;
    int jmax = q - kt + 1; if (jmax > 64) jmax = 64;
    for (int j=0;j<jmax;j++){
      float pj = __shfl(pp, j);
      oa += pj * b2f(Vb[(size_t)(kt+j)*HDIM + lane]);
    }
    m = mn;
  }
  out[(((size_t)(b*SEQ+q)*NH) + h)*HDIM + lane] = __float2bfloat16(oa / l);
}

// ---------------- router: fp32 RMS-norm + logits + softmax + top-2 ----------------
// Reads fp32 h1 directly so routing decisions are fp32-exact (bf16 logits can
// flip top-2 selection vs the fp32 reference -> O(0.5) output error).
__global__ __launch_bounds__(64) void k_router(const float* __restrict__ h1, const float* __restrict__ ln2w,
    const float* __restrict__ gw, float* __restrict__ scores,
    int* __restrict__ top_e, float* __restrict__ top_w, int* __restrict__ cnt){
  int tk = blockIdx.x, lane = threadIdx.x;
  const float* xr = h1 + (size_t)tk*DIM;
  // sum of squares (each lane owns 16 contiguous floats)
  const float4* x4 = (const float4*)xr;
  float4 xv[4];
  float ss = 0.f;
#pragma unroll
  for (int i=0;i<4;i++){
    xv[i] = x4[lane*4+i];
    ss += xv[i].x*xv[i].x + xv[i].y*xv[i].y + xv[i].z*xv[i].z + xv[i].w*xv[i].w;
  }
#pragma unroll
  for (int mm=1;mm<64;mm<<=1) ss += __shfl_xor(ss, mm);
  float r = rsqrtf(ss*(1.0f/DIM) + 1e-6f);
  // logits: acc[e] = sum_d xnorm[d]*gw[d][e]
  float acc[8] = {0,0,0,0,0,0,0,0};
#pragma unroll
  for (int i=0;i<16;i++){
    int d = lane*16 + i;
    float xd = ((const float*)xv)[i];
    float xn = xd * r * ln2w[d];
    const float* g = gw + (size_t)d*NE;
#pragma unroll
    for (int e=0;e<8;e++) acc[e] += xn * g[e];
  }
#pragma unroll
  for (int e=0;e<8;e++){
#pragma unroll
    for (int mm=1;mm<64;mm<<=1) acc[e] += __shfl_xor(acc[e], mm);
  }
  float mx = acc[0];
#pragma unroll
  for (int e=1;e<8;e++) mx = fmaxf(mx, acc[e]);
  float w[8]; float se = 0.f;
#pragma unroll
  for (int e=0;e<8;e++){ w[e] = expf(acc[e]-mx); se += w[e]; }
  float inv = 1.f/se;
#pragma unroll
  for (int e=0;e<8;e++) w[e] *= inv;
  if (lane < 8) scores[(size_t)tk*NE + lane] = w[lane];
  if (lane == 0){
    int e1=0; float m1=w[0];
#pragma unroll
    for (int i=1;i<8;i++) if (w[i] > m1){ m1=w[i]; e1=i; }
    int e2=-1; float m2=-1.f;
#pragma unroll
    for (int i=0;i<8;i++) if (i!=e1 && w[i] > m2){ m2=w[i]; e2=i; }
    float s12 = m1 + m2;
    top_e[2*tk] = e1;   top_w[2*tk]   = m1/s12;
    top_e[2*tk+1] = e2; top_w[2*tk+1] = m2/s12;
    atomicAdd(&cnt[e1], 1); atomicAdd(&cnt[e2], 1);
  }
}

// ---------------- 128-aligned segment offsets + tile->expert map ----------------
__global__ __launch_bounds__(256) void k_offsets(const int* __restrict__ cnt, int* __restrict__ seg_off,
    int* __restrict__ tile_expert, int* __restrict__ row_tok){
  int t = threadIdx.x;
  for (int i=t;i<MAXR;i+=256) row_tok[i] = -1;
  for (int i=t;i<MAXTILES;i+=256) tile_expert[i] = -1;
  __syncthreads();
  if (t == 0){
    int off = 0;
    for (int e=0;e<NE;e++){
      seg_off[e] = off;
      int nt = (cnt[e] + 127) >> 7;
      for (int i=0;i<nt;i++) tile_expert[(off>>7)+i] = e;
      off += nt << 7;
    }
  }
}

// ---------------- scatter token pairs into expert segments ----------------
__global__ __launch_bounds__(256) void k_scatter(const int* __restrict__ top_e, const float* __restrict__ top_w,
    const int* __restrict__ seg_off, int* __restrict__ cnt2,
    int* __restrict__ row_tok, float* __restrict__ row_w, int* __restrict__ row_slot){
  int tkn = blockIdx.x*256 + threadIdx.x;
  if (tkn >= NTOK) return;
#pragma unroll
  for (int k=0;k<2;k++){
    int e = top_e[2*tkn+k];
    int p = atomicAdd(&cnt2[e], 1);
    int r = seg_off[e] + p;
    row_tok[r] = tkn; row_w[r] = top_w[2*tkn+k]; row_slot[r] = k;
  }
}

// ---------------- gather xn2 rows into compacted Xg ----------------
__global__ __launch_bounds__(256) void k_gather(const int* __restrict__ row_tok, const bf16* __restrict__ xn,
    bf16* __restrict__ Xg){
  int r = blockIdx.x, t = threadIdx.x;
  int tok = row_tok[r];
  ushort4* dst = (ushort4*)(Xg + (size_t)r*DIM) + t;
  if (tok < 0){ ushort4 z; z.x=0; z.y=0; z.z=0; z.w=0; *dst = z; }
  else *dst = ((const ushort4*)(xn + (size_t)tok*DIM))[t];
}

// ---------------- h = silu(a) * b ----------------
__global__ __launch_bounds__(256) void k_silumul(const bf16* __restrict__ a, const bf16* __restrict__ b, bf16* __restrict__ o){
  size_t i = (size_t)blockIdx.x*256 + threadIdx.x;
  ushort4 ua = ((const ushort4*)a)[i];
  ushort4 ub = ((const ushort4*)b)[i];
  ushort4 uo;
  { float fa=b2f(ua.x), fb=b2f(ub.x); uo.x = f2b(fa/(1.f+__expf(-fa))*fb); }
  { float fa=b2f(ua.y), fb=b2f(ub.y); uo.y = f2b(fa/(1.f+__expf(-fa))*fb); }
  { float fa=b2f(ua.z), fb=b2f(ub.z); uo.z = f2b(fa/(1.f+__expf(-fa))*fb); }
  { float fa=b2f(ua.w), fb=b2f(ub.w); uo.w = f2b(fa/(1.f+__expf(-fa))*fb); }
  ((ushort4*)o)[i] = uo;
}

// ---------------- out = h1 + ybuf0 + ybuf1 ----------------
__global__ __launch_bounds__(256) void k_final(const float* __restrict__ h1, const float* __restrict__ ybuf, float* __restrict__ out){
  size_t i = (size_t)blockIdx.x*256 + threadIdx.x;
  float4 a  = ((const float4*)h1)[i];
  float4 b0 = ((const float4*)ybuf)[i];
  float4 b1 = ((const float4*)(ybuf + (size_t)NTOK*DIM))[i];
  float4 r;
  r.x = a.x+b0.x+b1.x; r.y = a.y+b0.y+b1.y; r.z = a.z+b0.z+b1.z; r.w = a.w+b0.w+b1.w;
  ((float4*)out)[i] = r;
}

extern "C" void kernel_launch(void* const* d_in, const int* in_sizes, int n_in,
                              void* d_out, int out_size, void* d_ws, size_t ws_size,
                              hipStream_t stream){
  const float* hidden = (const float*)d_in[0];
  const int*   pos    = (const int*)d_in[1];
  const float* ln1    = (const float*)d_in[3];
  const float* ln2    = (const float*)d_in[4];
  const float* wq     = (const float*)d_in[5];
  const float* wk     = (const float*)d_in[6];
  const float* wv     = (const float*)d_in[7];
  const float* wo     = (const float*)d_in[8];
  const float* gw     = (const float*)d_in[9];
  const float* w1     = (const float*)d_in[10];
  const float* w3     = (const float*)d_in[11];
  const float* w2     = (const float*)d_in[12];
  float* out1 = (float*)d_out;
  float* out2 = out1 + (size_t)NTOK*DIM;

  char* p = (char*)d_ws;
  auto take = [&](size_t bytes){ void* r = (void*)p; p += (bytes + 255) & ~(size_t)255; return r; };
  bf16* wqkvT = (bf16*)take((size_t)1536*1024*2);
  bf16* woT   = (bf16*)take((size_t)1024*1024*2);
  bf16* w1T   = (bf16*)take((size_t)NE*NF*DIM*2);
  bf16* w3T   = (bf16*)take((size_t)NE*NF*DIM*2);
  bf16* w2T   = (bf16*)take((size_t)NE*DIM*NF*2);
  float* h1   = (float*)take((size_t)NTOK*DIM*4);
  bf16* xn2   = (bf16*)take((size_t)NTOK*DIM*2);
  int*  cnt   = (int*)take(64);          // cnt[8] then cnt2[8]
  int*  cnt2  = cnt + 8;
  int*  seg_off     = (int*)take(64);
  int*  tile_expert = (int*)take(MAXTILES*4);
  int*  top_e  = (int*)take((size_t)NTOK*2*4);
  float* top_w = (float*)take((size_t)NTOK*2*4);
  int*  row_tok  = (int*)take((size_t)MAXR*4);
  float* row_w   = (float*)take((size_t)MAXR*4);
  int*  row_slot = (int*)take((size_t)MAXR*4);
  bf16* Xg    = (bf16*)take((size_t)MAXR*DIM*2);
  bf16* h1buf = (bf16*)take((size_t)MAXR*NF*2);
  bf16* h3buf = (bf16*)take((size_t)MAXR*NF*2);
  bf16* hbuf  = (bf16*)take((size_t)MAXR*NF*2);
  // region A overlays Xg+h1buf (30MB); all dead before Xg/h1buf written
  char* ra = (char*)Xg;
  bf16* xn1 = (bf16*)ra;       ra += (size_t)NTOK*DIM*2;
  bf16* qkv = (bf16*)ra;       ra += (size_t)NTOK*1536*2;
  bf16* qr  = (bf16*)ra;       ra += (size_t)NTOK*DIM*2;
  bf16* krp = (bf16*)ra;       ra += (size_t)NTOK*NKV*HDIM*2; // [B,KV,S,HD] = 524288 elems = 1MB
  bf16* vrp = (bf16*)ra;       ra += (size_t)NTOK*NKV*HDIM*2;
  bf16* attn_out = (bf16*)ra;  ra += (size_t)NTOK*DIM*2;
  float* ybuf = (float*)h1buf; // [2][NTOK][DIM] fp32 (16MB <= 20MB), h1buf dead by then

  // 0) zero counters
  k_zero_i32<<<dim3(1), dim3(256), 0, stream>>>(cnt, 16);
  // 1) weight transposes (fp32 -> bf16, B^T layout)
  k_transpose<<<dim3(32,32,1), dim3(32,8), 0, stream>>>(wq, wqkvT, 1024, 1024);
  k_transpose<<<dim3(8,32,1),  dim3(32,8), 0, stream>>>(wk, wqkvT + (size_t)1024*1024, 1024, 256);
  k_transpose<<<dim3(8,32,1),  dim3(32,8), 0, stream>>>(wv, wqkvT + (size_t)1280*1024, 1024, 256);
  k_transpose<<<dim3(32,32,1), dim3(32,8), 0, stream>>>(wo, woT, 1024, 1024);
  k_transpose<<<dim3(NF/32, DIM/32, NE), dim3(32,8), 0, stream>>>(w1, w1T, DIM, NF);
  k_transpose<<<dim3(NF/32, DIM/32, NE), dim3(32,8), 0, stream>>>(w3, w3T, DIM, NF);
  k_transpose<<<dim3(DIM/32, NF/32, NE), dim3(32,8), 0, stream>>>(w2, w2T, NF, DIM);
  // 2) ln1
  k_rmsnorm<<<dim3(NTOK), dim3(256), 0, stream>>>(hidden, ln1, xn1);
  // 3) qkv projection
  k_gemm<0><<<dim3(1536/BN, NTOK/BM), dim3(256), 0, stream>>>(xn1, wqkvT, qkv, nullptr, nullptr, nullptr, nullptr, nullptr, nullptr, 1536, 1024);
  // 4) rope + reshape
  k_rope<<<dim3(NTOK), dim3(64), 0, stream>>>(qkv, pos, qr, krp, vrp);
  // 5) attention
  k_attn<<<dim3(SEQ, NH, 2), dim3(64), 0, stream>>>(qr, krp, vrp, attn_out);
  // 6) o-proj + residual -> h1 (fp32)
  k_gemm<1><<<dim3(DIM/BN, NTOK/BM), dim3(256), 0, stream>>>(attn_out, woT, nullptr, h1, hidden, nullptr, nullptr, nullptr, nullptr, DIM, 1024);
  // 7) ln2 (bf16 xn2 for expert inputs only; router reads fp32 h1)
  k_rmsnorm<<<dim3(NTOK), dim3(256), 0, stream>>>(h1, ln2, xn2);
  // 8) router (fp32-exact routing; writes gate_scores output)
  k_router<<<dim3(NTOK), dim3(64), 0, stream>>>(h1, ln2, gw, out2, top_e, top_w, cnt);
  // 9) segment offsets + tile map
  k_offsets<<<dim3(1), dim3(256), 0, stream>>>(cnt, seg_off, tile_expert, row_tok);
  // 10) scatter pairs
  k_scatter<<<dim3(NTOK/256), dim3(256), 0, stream>>>(top_e, top_w, seg_off, cnt2, row_tok, row_w, row_slot);
  // 11) gather rows
  k_gather<<<dim3(MAXR), dim3(256), 0, stream>>>(row_tok, xn2, Xg);
  // 12) expert GEMM1 (w1, w3)
  k_gemm<2><<<dim3(NF/BN, MAXTILES), dim3(256), 0, stream>>>(Xg, w1T, h1buf, nullptr, nullptr, tile_expert, nullptr, nullptr, nullptr, NF, DIM);
  k_gemm<2><<<dim3(NF/BN, MAXTILES), dim3(256), 0, stream>>>(Xg, w3T, h3buf, nullptr, nullptr, tile_expert, nullptr, nullptr, nullptr, NF, DIM);
  // 13) swiglu
  k_silumul<<<dim3((unsigned)((size_t)MAXR*NF/4/256)), dim3(256), 0, stream>>>(h1buf, h3buf, hbuf);
  // 14) expert GEMM2 -> ybuf (weighted, scattered)
  k_gemm<3><<<dim3(DIM/BN, MAXTILES), dim3(256), 0, stream>>>(hbuf, w2T, nullptr, ybuf, nullptr, tile_expert, row_tok, row_w, row_slot, DIM, NF);
  // 15) final residual add
  k_final<<<dim3(NTOK*DIM/4/256), dim3(256), 0, stream>>>(h1, ybuf, out1);
}

// Round 4
// 621.930 us; speedup vs baseline: 2.5349x; 2.5349x over previous
//
#include <hip/hip_runtime.h>
#include <hip/hip_bf16.h>
#include <stdint.h>

using bf16 = __hip_bfloat16;
using bf16x8 = __attribute__((ext_vector_type(8))) __bf16;
using f32x4  = __attribute__((ext_vector_type(4))) float;

#define NTOK 2048
#define DIM 1024
#define NH 16
#define NKV 4
#define HDIM 64
#define NE 8
#define NF 2048
#define SEQ 1024
#define MAXR 5120      // 4096 pairs + 8*128 alignment slack
#define MAXTILES 40

__device__ __forceinline__ float b2f(unsigned short u){ unsigned v=((unsigned)u)<<16; float f; __builtin_memcpy(&f,&v,4); return f; }
__device__ __forceinline__ unsigned short f2b(float f){ bf16 h=__float2bfloat16(f); unsigned short u; __builtin_memcpy(&u,&h,2); return u; }

// ---------------- zero small int buffers ----------------
__global__ void k_zero_i32(int* p, int n){ int i=blockIdx.x*256+threadIdx.x; if(i<n) p[i]=0; }

// ---------------- transpose+cast: fp32 [Z][R][C] -> bf16 [Z][C][R] ----------------
__global__ __launch_bounds__(256) void k_transpose(const float* __restrict__ in, bf16* __restrict__ out, int R, int C){
  __shared__ float tile[32][33];
  int bx = blockIdx.x*32, by = blockIdx.y*32;
  size_t base = (size_t)blockIdx.z * R * C;
  int x = threadIdx.x, y0 = threadIdx.y;
  const float* src = in + base;
  bf16* dst = out + base;
#pragma unroll
  for (int i=0;i<4;i++){ int r = y0 + i*8; tile[r][x] = src[(size_t)(by+r)*C + bx + x]; }
  __syncthreads();
#pragma unroll
  for (int i=0;i<4;i++){ int c = y0 + i*8; dst[(size_t)(bx+c)*R + by + x] = __float2bfloat16(tile[x][c]); }
}

// ---------------- bf16 transpose: [Z][R][C] -> [Z][C][R] ----------------
__global__ __launch_bounds__(256) void k_tbf(const bf16* __restrict__ in, bf16* __restrict__ out, int R, int C){
  __shared__ unsigned short tile[32][33];
  int bx = blockIdx.x*32, by = blockIdx.y*32;
  size_t base = (size_t)blockIdx.z * R * C;
  const unsigned short* src = (const unsigned short*)in + base;
  unsigned short* dst = (unsigned short*)out + base;
  int x = threadIdx.x, y0 = threadIdx.y;
#pragma unroll
  for (int i=0;i<4;i++){ int r = y0 + i*8; tile[r][x] = src[(size_t)(by+r)*C + bx + x]; }
  __syncthreads();
#pragma unroll
  for (int i=0;i<4;i++){ int c = y0 + i*8; dst[(size_t)(bx+c)*R + by + x] = tile[x][c]; }
}

// ---------------- RMSNorm fp32 -> bf16 ----------------
__global__ __launch_bounds__(256) void k_rmsnorm(const float* __restrict__ x, const float* __restrict__ w, bf16* __restrict__ out){
  int row = blockIdx.x, t = threadIdx.x;
  const float4 v = ((const float4*)(x + (size_t)row*DIM))[t];
  float ss = v.x*v.x + v.y*v.y + v.z*v.z + v.w*v.w;
#pragma unroll
  for (int m=1;m<64;m<<=1) ss += __shfl_xor(ss, m);
  __shared__ float red[4];
  if ((t&63)==0) red[t>>6] = ss;
  __syncthreads();
  float tot = red[0]+red[1]+red[2]+red[3];
  float r = rsqrtf(tot * (1.0f/DIM) + 1e-6f);
  const float4 wv = ((const float4*)w)[t];
  ushort4 o;
  o.x = f2b(v.x*r*wv.x); o.y = f2b(v.y*r*wv.y); o.z = f2b(v.z*r*wv.z); o.w = f2b(v.w*r*wv.w);
  ((ushort4*)(out + (size_t)row*DIM))[t] = o;
}

// ---------------- MFMA GEMM: A[M x K] row-major, Bt[N x K] row-major ----------------
// MODE 0: C bf16            MODE 1: C fp32 = acc + resid
// MODE 2: per-expert B (tile map), C bf16
// MODE 3: per-expert B (tile map), scatter to ybuf[slot][tok][col] = acc*w
#define BM 128
#define BN 128
#define BK 32

template<int MODE>
__global__ __launch_bounds__(256) void k_gemm(
    const bf16* __restrict__ A, const bf16* __restrict__ Bt,
    bf16* __restrict__ Cb, float* __restrict__ Cf, const float* __restrict__ resid,
    const int* __restrict__ tile_expert, const int* __restrict__ row_tok,
    const float* __restrict__ row_w, const int* __restrict__ row_slot,
    int N, int K)
{
  int tn = blockIdx.x, tm = blockIdx.y;
  int e = 0;
  if constexpr (MODE >= 2){ e = tile_expert[tm]; if (e < 0) return; }
  const bf16* Ablk = A + (size_t)tm*BM*K;
  const bf16* Bblk = Bt + ((MODE>=2) ? (size_t)e*N*K : (size_t)0) + (size_t)tn*BN*K;

  __shared__ bf16 lA[BM*BK];
  __shared__ bf16 lB[BN*BK];

  int t = threadIdx.x;
  int lane = t & 63, wave = t >> 6;
  int wr = wave >> 1, wc = wave & 1;
  int lr = lane & 15, lg = lane >> 4;

  int sr = t >> 2;        // staging row within 64-row chunk
  int sk = (t & 3) * 8;   // staging k offset

  f32x4 acc[4][4] = {};

  for (int k0 = 0; k0 < K; k0 += BK){
    bf16x8 va0 = *(const bf16x8*)(Ablk + (size_t)sr*K + k0 + sk);
    bf16x8 va1 = *(const bf16x8*)(Ablk + (size_t)(64+sr)*K + k0 + sk);
    bf16x8 vb0 = *(const bf16x8*)(Bblk + (size_t)sr*K + k0 + sk);
    bf16x8 vb1 = *(const bf16x8*)(Bblk + (size_t)(64+sr)*K + k0 + sk);
    __syncthreads();
    *(bf16x8*)(lA + t*8) = va0;
    *(bf16x8*)(lA + 2048 + t*8) = va1;
    *(bf16x8*)(lB + t*8) = vb0;
    *(bf16x8*)(lB + 2048 + t*8) = vb1;
    __syncthreads();
    bf16x8 af[4], bfv[4];
#pragma unroll
    for (int m=0;m<4;m++) af[m]  = *(const bf16x8*)(lA + (wr*64 + m*16 + lr)*BK + lg*8);
#pragma unroll
    for (int n=0;n<4;n++) bfv[n] = *(const bf16x8*)(lB + (wc*64 + n*16 + lr)*BK + lg*8);
#pragma unroll
    for (int m=0;m<4;m++)
#pragma unroll
      for (int n=0;n<4;n++)
        acc[m][n] = __builtin_amdgcn_mfma_f32_16x16x32_bf16(af[m], bfv[n], acc[m][n], 0, 0, 0);
  }

#pragma unroll
  for (int m=0;m<4;m++){
#pragma unroll
    for (int n=0;n<4;n++){
      int col = tn*BN + wc*64 + n*16 + lr;
#pragma unroll
      for (int j=0;j<4;j++){
        int row = tm*BM + wr*64 + m*16 + lg*4 + j;
        float v = acc[m][n][j];
        if constexpr (MODE==0 || MODE==2){
          Cb[(size_t)row*N + col] = __float2bfloat16(v);
        } else if constexpr (MODE==1){
          Cf[(size_t)row*N + col] = v + resid[(size_t)row*N + col];
        } else {
          int tok = row_tok[row];
          if (tok >= 0) Cf[((size_t)row_slot[row]*NTOK + tok)*DIM + col] = v * row_w[row];
        }
      }
    }
  }
}

// ---------------- RoPE + reshape qkv[T][1536] -> qr[B,H,S,HD], kr/vr[B,KV,S,HD] ----------------
__global__ __launch_bounds__(64) void k_rope(const bf16* __restrict__ qkv, const int* __restrict__ pos_ids,
    bf16* __restrict__ qr, bf16* __restrict__ kr, bf16* __restrict__ vr){
  int tk = blockIdx.x;
  int b = tk >> 10, s = tk & 1023;
  int d = threadIdx.x;
  float p = (float)pos_ids[tk];
  int i = d & 31;
  float freq = p * powf(10000.0f, -(float)(2*i)*(1.0f/HDIM));
  float sn, cs;
  sincosf(freq, &sn, &cs);
  const bf16* row = qkv + (size_t)tk*1536;
#pragma unroll
  for (int h=0; h<NH; h++){
    float x  = __bfloat162float(row[h*64 + d]);
    float xp = __bfloat162float(row[h*64 + ((d+32)&63)]);
    float rh = (d<32) ? -xp : xp;
    qr[(((size_t)(b*NH+h)*SEQ)+s)*HDIM + d] = __float2bfloat16(x*cs + rh*sn);
  }
#pragma unroll
  for (int h=0; h<NKV; h++){
    float x  = __bfloat162float(row[1024 + h*64 + d]);
    float xp = __bfloat162float(row[1024 + h*64 + ((d+32)&63)]);
    float rh = (d<32) ? -xp : xp;
    kr[(((size_t)(b*NKV+h)*SEQ)+s)*HDIM + d] = __float2bfloat16(x*cs + rh*sn);
    vr[(((size_t)(b*NKV+h)*SEQ)+s)*HDIM + d] = row[1280 + h*64 + d];
  }
}

// ---------------- MFMA flash attention ----------------
// 1 wave per (b, h, 16-row q-tile). KVBLK=32.
// QK^T: A-frag = Q[row=c][d] (16B global), B-frag = K[col=c][d] (16B global).
// Softmax in C-layout (row=g*4+j, col=c); P via padded LDS -> PV A-frag.
// PV B-frag from pre-transposed vT[d][s] (16B global).
__global__ __launch_bounds__(64) void k_attn_mfma(const bf16* __restrict__ qr, const bf16* __restrict__ kr,
    const bf16* __restrict__ vT, bf16* __restrict__ out){
  int qt = blockIdx.x, h = blockIdx.y, b = blockIdx.z;
  int lane = threadIdx.x;
  int g = lane >> 4, c = lane & 15;
  int kv = h >> 2;
  int qbase = qt*16;
  const bf16* Qb = qr + (((size_t)(b*NH+h)*SEQ) + qbase)*HDIM;
  const bf16* Kb = kr + ((size_t)(b*NKV+kv)*SEQ)*HDIM;
  const bf16* Vt = vT + ((size_t)(b*NKV+kv)*HDIM)*SEQ;

  bf16x8 qa[2];
  qa[0] = *(const bf16x8*)(Qb + (size_t)c*HDIM + g*8);
  qa[1] = *(const bf16x8*)(Qb + (size_t)c*HDIM + 32 + g*8);

  f32x4 acc[4] = {};            // O frags, d-blocks 0..3
  float m[4], l[4];
#pragma unroll
  for (int j=0;j<4;j++){ m[j] = -1e30f; l[j] = 0.f; }

  __shared__ bf16 P[16][40];    // pitch 40 (80B): conflict-free b128 reads

  int kend = qbase + 15;
  for (int k0 = 0; k0 <= kend; k0 += 32){
    f32x4 s[2] = {};
#pragma unroll
    for (int cn=0;cn<2;cn++){
#pragma unroll
      for (int dk=0;dk<2;dk++){
        bf16x8 kb = *(const bf16x8*)(Kb + (size_t)(k0+cn*16+c)*HDIM + dk*32 + g*8);
        s[cn] = __builtin_amdgcn_mfma_f32_16x16x32_bf16(qa[dk], kb, s[cn], 0, 0, 0);
      }
    }
    float sv[2][4];
    bool boundary = (k0 + 31 > qbase);
#pragma unroll
    for (int cn=0;cn<2;cn++){
#pragma unroll
      for (int j=0;j<4;j++){
        float v = s[cn][j] * 0.125f;
        if (boundary){
          int cg = k0 + cn*16 + c, rg = qbase + g*4 + j;
          if (cg > rg) v = -1e30f;
        }
        sv[cn][j] = v;
      }
    }
#pragma unroll
    for (int j=0;j<4;j++){
      float rmax = fmaxf(sv[0][j], sv[1][j]);
#pragma unroll
      for (int mk=1;mk<16;mk<<=1) rmax = fmaxf(rmax, __shfl_xor(rmax, mk));
      float mn = fmaxf(m[j], rmax);
      float corr = __expf(m[j] - mn);
      m[j] = mn;
      float p0 = __expf(sv[0][j] - mn);
      float p1 = __expf(sv[1][j] - mn);
      float rs = p0 + p1;
#pragma unroll
      for (int mk=1;mk<16;mk<<=1) rs += __shfl_xor(rs, mk);
      l[j] = l[j]*corr + rs;
#pragma unroll
      for (int db=0;db<4;db++) acc[db][j] *= corr;
      P[g*4+j][c]      = __float2bfloat16(p0);
      P[g*4+j][16+c]   = __float2bfloat16(p1);
    }
    __syncthreads();
    bf16x8 pa = *(const bf16x8*)(&P[c][g*8]);
#pragma unroll
    for (int db=0;db<4;db++){
      bf16x8 vb = *(const bf16x8*)(Vt + (size_t)(db*16+c)*SEQ + k0 + g*8);
      acc[db] = __builtin_amdgcn_mfma_f32_16x16x32_bf16(pa, vb, acc[db], 0, 0, 0);
    }
    __syncthreads();
  }
#pragma unroll
  for (int j=0;j<4;j++){
    float inv = 1.f / l[j];
    size_t rowoff = (size_t)(b*SEQ + qbase + g*4 + j)*1024 + h*64;
#pragma unroll
    for (int db=0;db<4;db++)
      out[rowoff + db*16 + c] = __float2bfloat16(acc[db][j] * inv);
  }
}

// ---------------- router: fp32 RMS-norm + logits + softmax + top-2 ----------------
__global__ __launch_bounds__(64) void k_router(const float* __restrict__ h1, const float* __restrict__ ln2w,
    const float* __restrict__ gw, float* __restrict__ scores,
    int* __restrict__ top_e, float* __restrict__ top_w, int* __restrict__ cnt){
  int tk = blockIdx.x, lane = threadIdx.x;
  const float* xr = h1 + (size_t)tk*DIM;
  const float4* x4 = (const float4*)xr;
  float4 xv[4];
  float ss = 0.f;
#pragma unroll
  for (int i=0;i<4;i++){
    xv[i] = x4[lane*4+i];
    ss += xv[i].x*xv[i].x + xv[i].y*xv[i].y + xv[i].z*xv[i].z + xv[i].w*xv[i].w;
  }
#pragma unroll
  for (int mm=1;mm<64;mm<<=1) ss += __shfl_xor(ss, mm);
  float r = rsqrtf(ss*(1.0f/DIM) + 1e-6f);
  float acc[8] = {0,0,0,0,0,0,0,0};
#pragma unroll
  for (int i=0;i<16;i++){
    int d = lane*16 + i;
    float xd = ((const float*)xv)[i];
    float xn = xd * r * ln2w[d];
    const float* g = gw + (size_t)d*NE;
#pragma unroll
    for (int e=0;e<8;e++) acc[e] += xn * g[e];
  }
#pragma unroll
  for (int e=0;e<8;e++){
#pragma unroll
    for (int mm=1;mm<64;mm<<=1) acc[e] += __shfl_xor(acc[e], mm);
  }
  float mx = acc[0];
#pragma unroll
  for (int e=1;e<8;e++) mx = fmaxf(mx, acc[e]);
  float w[8]; float se = 0.f;
#pragma unroll
  for (int e=0;e<8;e++){ w[e] = expf(acc[e]-mx); se += w[e]; }
  float inv = 1.f/se;
#pragma unroll
  for (int e=0;e<8;e++) w[e] *= inv;
  if (lane < 8) scores[(size_t)tk*NE + lane] = w[lane];
  if (lane == 0){
    int e1=0; float m1=w[0];
#pragma unroll
    for (int i=1;i<8;i++) if (w[i] > m1){ m1=w[i]; e1=i; }
    int e2=-1; float m2=-1.f;
#pragma unroll
    for (int i=0;i<8;i++) if (i!=e1 && w[i] > m2){ m2=w[i]; e2=i; }
    float s12 = m1 + m2;
    top_e[2*tk] = e1;   top_w[2*tk]   = m1/s12;
    top_e[2*tk+1] = e2; top_w[2*tk+1] = m2/s12;
    atomicAdd(&cnt[e1], 1); atomicAdd(&cnt[e2], 1);
  }
}

// ---------------- 128-aligned segment offsets + tile->expert map ----------------
__global__ __launch_bounds__(256) void k_offsets(const int* __restrict__ cnt, int* __restrict__ seg_off,
    int* __restrict__ tile_expert, int* __restrict__ row_tok){
  int t = threadIdx.x;
  for (int i=t;i<MAXR;i+=256) row_tok[i] = -1;
  for (int i=t;i<MAXTILES;i+=256) tile_expert[i] = -1;
  __syncthreads();
  if (t == 0){
    int off = 0;
    for (int e=0;e<NE;e++){
      seg_off[e] = off;
      int nt = (cnt[e] + 127) >> 7;
      for (int i=0;i<nt;i++) tile_expert[(off>>7)+i] = e;
      off += nt << 7;
    }
  }
}

// ---------------- scatter token pairs into expert segments ----------------
__global__ __launch_bounds__(256) void k_scatter(const int* __restrict__ top_e, const float* __restrict__ top_w,
    const int* __restrict__ seg_off, int* __restrict__ cnt2,
    int* __restrict__ row_tok, float* __restrict__ row_w, int* __restrict__ row_slot){
  int tkn = blockIdx.x*256 + threadIdx.x;
  if (tkn >= NTOK) return;
#pragma unroll
  for (int k=0;k<2;k++){
    int e = top_e[2*tkn+k];
    int p = atomicAdd(&cnt2[e], 1);
    int r = seg_off[e] + p;
    row_tok[r] = tkn; row_w[r] = top_w[2*tkn+k]; row_slot[r] = k;
  }
}

// ---------------- gather xn2 rows into compacted Xg ----------------
__global__ __launch_bounds__(256) void k_gather(const int* __restrict__ row_tok, const bf16* __restrict__ xn,
    bf16* __restrict__ Xg){
  int r = blockIdx.x, t = threadIdx.x;
  int tok = row_tok[r];
  ushort4* dst = (ushort4*)(Xg + (size_t)r*DIM) + t;
  if (tok < 0){ ushort4 z; z.x=0; z.y=0; z.z=0; z.w=0; *dst = z; }
  else *dst = ((const ushort4*)(xn + (size_t)tok*DIM))[t];
}

// ---------------- h = silu(a) * b ----------------
__global__ __launch_bounds__(256) void k_silumul(const bf16* __restrict__ a, const bf16* __restrict__ b, bf16* __restrict__ o){
  size_t i = (size_t)blockIdx.x*256 + threadIdx.x;
  ushort4 ua = ((const ushort4*)a)[i];
  ushort4 ub = ((const ushort4*)b)[i];
  ushort4 uo;
  { float fa=b2f(ua.x), fb=b2f(ub.x); uo.x = f2b(fa/(1.f+__expf(-fa))*fb); }
  { float fa=b2f(ua.y), fb=b2f(ub.y); uo.y = f2b(fa/(1.f+__expf(-fa))*fb); }
  { float fa=b2f(ua.z), fb=b2f(ub.z); uo.z = f2b(fa/(1.f+__expf(-fa))*fb); }
  { float fa=b2f(ua.w), fb=b2f(ub.w); uo.w = f2b(fa/(1.f+__expf(-fa))*fb); }
  ((ushort4*)o)[i] = uo;
}

// ---------------- out = h1 + ybuf0 + ybuf1 ----------------
__global__ __launch_bounds__(256) void k_final(const float* __restrict__ h1, const float* __restrict__ ybuf, float* __restrict__ out){
  size_t i = (size_t)blockIdx.x*256 + threadIdx.x;
  float4 a  = ((const float4*)h1)[i];
  float4 b0 = ((const float4*)ybuf)[i];
  float4 b1 = ((const float4*)(ybuf + (size_t)NTOK*DIM))[i];
  float4 r;
  r.x = a.x+b0.x+b1.x; r.y = a.y+b0.y+b1.y; r.z = a.z+b0.z+b1.z; r.w = a.w+b0.w+b1.w;
  ((float4*)out)[i] = r;
}

extern "C" void kernel_launch(void* const* d_in, const int* in_sizes, int n_in,
                              void* d_out, int out_size, void* d_ws, size_t ws_size,
                              hipStream_t stream){
  const float* hidden = (const float*)d_in[0];
  const int*   pos    = (const int*)d_in[1];
  const float* ln1    = (const float*)d_in[3];
  const float* ln2    = (const float*)d_in[4];
  const float* wq     = (const float*)d_in[5];
  const float* wk     = (const float*)d_in[6];
  const float* wv     = (const float*)d_in[7];
  const float* wo     = (const float*)d_in[8];
  const float* gw     = (const float*)d_in[9];
  const float* w1     = (const float*)d_in[10];
  const float* w3     = (const float*)d_in[11];
  const float* w2     = (const float*)d_in[12];
  float* out1 = (float*)d_out;
  float* out2 = out1 + (size_t)NTOK*DIM;

  char* p = (char*)d_ws;
  auto take = [&](size_t bytes){ void* r = (void*)p; p += (bytes + 255) & ~(size_t)255; return r; };
  bf16* wqkvT = (bf16*)take((size_t)1536*1024*2);
  bf16* woT   = (bf16*)take((size_t)1024*1024*2);
  bf16* w1T   = (bf16*)take((size_t)NE*NF*DIM*2);
  bf16* w3T   = (bf16*)take((size_t)NE*NF*DIM*2);
  bf16* w2T   = (bf16*)take((size_t)NE*DIM*NF*2);
  float* h1   = (float*)take((size_t)NTOK*DIM*4);
  bf16* xn2   = (bf16*)take((size_t)NTOK*DIM*2);
  int*  cnt   = (int*)take(64);          // cnt[8] then cnt2[8]
  int*  cnt2  = cnt + 8;
  int*  seg_off     = (int*)take(64);
  int*  tile_expert = (int*)take(MAXTILES*4);
  int*  top_e  = (int*)take((size_t)NTOK*2*4);
  float* top_w = (float*)take((size_t)NTOK*2*4);
  int*  row_tok  = (int*)take((size_t)MAXR*4);
  float* row_w   = (float*)take((size_t)MAXR*4);
  int*  row_slot = (int*)take((size_t)MAXR*4);
  bf16* Xg    = (bf16*)take((size_t)MAXR*DIM*2);
  bf16* h1buf = (bf16*)take((size_t)MAXR*NF*2);
  bf16* h3buf = (bf16*)take((size_t)MAXR*NF*2);
  bf16* hbuf  = (bf16*)take((size_t)MAXR*NF*2);
  // region A overlays Xg+h1buf (30MB); all dead before Xg/h1buf written
  char* ra = (char*)Xg;
  bf16* xn1 = (bf16*)ra;       ra += (size_t)NTOK*DIM*2;
  bf16* qkv = (bf16*)ra;       ra += (size_t)NTOK*1536*2;
  bf16* qr  = (bf16*)ra;       ra += (size_t)NTOK*DIM*2;
  bf16* krp = (bf16*)ra;       ra += (size_t)NTOK*NKV*HDIM*2; // 1MB
  bf16* vrp = (bf16*)ra;       ra += (size_t)NTOK*NKV*HDIM*2;
  bf16* vTp = (bf16*)ra;       ra += (size_t)NTOK*NKV*HDIM*2; // [B*KV][HD][S]
  bf16* attn_out = (bf16*)ra;  ra += (size_t)NTOK*DIM*2;
  float* ybuf = (float*)h1buf; // [2][NTOK][DIM] fp32 (16MB <= 20MB), h1buf dead by then

  // 0) zero counters
  k_zero_i32<<<dim3(1), dim3(256), 0, stream>>>(cnt, 16);
  // 1) weight transposes (fp32 -> bf16, B^T layout)
  k_transpose<<<dim3(32,32,1), dim3(32,8), 0, stream>>>(wq, wqkvT, 1024, 1024);
  k_transpose<<<dim3(8,32,1),  dim3(32,8), 0, stream>>>(wk, wqkvT + (size_t)1024*1024, 1024, 256);
  k_transpose<<<dim3(8,32,1),  dim3(32,8), 0, stream>>>(wv, wqkvT + (size_t)1280*1024, 1024, 256);
  k_transpose<<<dim3(32,32,1), dim3(32,8), 0, stream>>>(wo, woT, 1024, 1024);
  k_transpose<<<dim3(NF/32, DIM/32, NE), dim3(32,8), 0, stream>>>(w1, w1T, DIM, NF);
  k_transpose<<<dim3(NF/32, DIM/32, NE), dim3(32,8), 0, stream>>>(w3, w3T, DIM, NF);
  k_transpose<<<dim3(DIM/32, NF/32, NE), dim3(32,8), 0, stream>>>(w2, w2T, NF, DIM);
  // 2) ln1
  k_rmsnorm<<<dim3(NTOK), dim3(256), 0, stream>>>(hidden, ln1, xn1);
  // 3) qkv projection
  k_gemm<0><<<dim3(1536/BN, NTOK/BM), dim3(256), 0, stream>>>(xn1, wqkvT, qkv, nullptr, nullptr, nullptr, nullptr, nullptr, nullptr, 1536, 1024);
  // 4) rope + reshape
  k_rope<<<dim3(NTOK), dim3(64), 0, stream>>>(qkv, pos, qr, krp, vrp);
  // 4b) V transpose -> [d][s]
  k_tbf<<<dim3(HDIM/32, SEQ/32, 2*NKV), dim3(32,8), 0, stream>>>(vrp, vTp, SEQ, HDIM);
  // 5) attention (MFMA flash)
  k_attn_mfma<<<dim3(SEQ/16, NH, 2), dim3(64), 0, stream>>>(qr, krp, vTp, attn_out);
  // 6) o-proj + residual -> h1 (fp32)
  k_gemm<1><<<dim3(DIM/BN, NTOK/BM), dim3(256), 0, stream>>>(attn_out, woT, nullptr, h1, hidden, nullptr, nullptr, nullptr, nullptr, DIM, 1024);
  // 7) ln2 (bf16 xn2 for expert inputs; router reads fp32 h1)
  k_rmsnorm<<<dim3(NTOK), dim3(256), 0, stream>>>(h1, ln2, xn2);
  // 8) router (fp32-exact routing; writes gate_scores output)
  k_router<<<dim3(NTOK), dim3(64), 0, stream>>>(h1, ln2, gw, out2, top_e, top_w, cnt);
  // 9) segment offsets + tile map
  k_offsets<<<dim3(1), dim3(256), 0, stream>>>(cnt, seg_off, tile_expert, row_tok);
  // 10) scatter pairs
  k_scatter<<<dim3(NTOK/256), dim3(256), 0, stream>>>(top_e, top_w, seg_off, cnt2, row_tok, row_w, row_slot);
  // 11) gather rows
  k_gather<<<dim3(MAXR), dim3(256), 0, stream>>>(row_tok, xn2, Xg);
  // 12) expert GEMM1 (w1, w3)
  k_gemm<2><<<dim3(NF/BN, MAXTILES), dim3(256), 0, stream>>>(Xg, w1T, h1buf, nullptr, nullptr, tile_expert, nullptr, nullptr, nullptr, NF, DIM);
  k_gemm<2><<<dim3(NF/BN, MAXTILES), dim3(256), 0, stream>>>(Xg, w3T, h3buf, nullptr, nullptr, tile_expert, nullptr, nullptr, nullptr, NF, DIM);
  // 13) swiglu
  k_silumul<<<dim3((unsigned)((size_t)MAXR*NF/4/256)), dim3(256), 0, stream>>>(h1buf, h3buf, hbuf);
  // 14) expert GEMM2 -> ybuf (weighted, scattered)
  k_gemm<3><<<dim3(DIM/BN, MAXTILES), dim3(256), 0, stream>>>(hbuf, w2T, nullptr, ybuf, nullptr, tile_expert, row_tok, row_w, row_slot, DIM, NF);
  // 15) final residual add
  k_final<<<dim3(NTOK*DIM/4/256), dim3(256), 0, stream>>>(h1, ybuf, out1);
}

// Round 5
// 617.019 us; speedup vs baseline: 2.5551x; 1.0080x over previous
//
#include <hip/hip_runtime.h>
#include <hip/hip_bf16.h>
#include <stdint.h>

using bf16 = __hip_bfloat16;
using bf16x8 = __attribute__((ext_vector_type(8))) __bf16;
using f32x4  = __attribute__((ext_vector_type(4))) float;

#define NTOK 2048
#define DIM 1024
#define NH 16
#define NKV 4
#define HDIM 64
#define NE 8
#define NF 2048
#define SEQ 1024
#define MAXR 5120      // 4096 pairs + 8*128 alignment slack
#define MAXTILES 40

__device__ __forceinline__ float b2f(unsigned short u){ unsigned v=((unsigned)u)<<16; float f; __builtin_memcpy(&f,&v,4); return f; }
__device__ __forceinline__ unsigned short f2b(float f){ bf16 h=__float2bfloat16(f); unsigned short u; __builtin_memcpy(&u,&h,2); return u; }

typedef __attribute__((address_space(3))) unsigned int lds_u32;
typedef const __attribute__((address_space(1))) unsigned int glb_u32;
__device__ __forceinline__ void lds16(const void* g, void* l){
  __builtin_amdgcn_global_load_lds((glb_u32*)g, (lds_u32*)l, 16, 0, 0);
}

// ---------------- zero small int buffers ----------------
__global__ void k_zero_i32(int* p, int n){ int i=blockIdx.x*256+threadIdx.x; if(i<n) p[i]=0; }

// ---------------- transpose+cast: fp32 [Z][R][C] -> bf16 [Z][C][R] ----------------
__global__ __launch_bounds__(256) void k_transpose(const float* __restrict__ in, bf16* __restrict__ out,
    int R, int C, size_t inz, size_t outz){
  __shared__ float tile[32][33];
  int bx = blockIdx.x*32, by = blockIdx.y*32;
  const float* src = in + (size_t)blockIdx.z * inz;
  bf16* dst = out + (size_t)blockIdx.z * outz;
  int x = threadIdx.x, y0 = threadIdx.y;
#pragma unroll
  for (int i=0;i<4;i++){ int r = y0 + i*8; tile[r][x] = src[(size_t)(by+r)*C + bx + x]; }
  __syncthreads();
#pragma unroll
  for (int i=0;i<4;i++){ int c = y0 + i*8; dst[(size_t)(bx+c)*R + by + x] = __float2bfloat16(tile[x][c]); }
}

// ---------------- bf16 transpose: [Z][R][C] -> [Z][C][R] ----------------
__global__ __launch_bounds__(256) void k_tbf(const bf16* __restrict__ in, bf16* __restrict__ out, int R, int C){
  __shared__ unsigned short tile[32][33];
  int bx = blockIdx.x*32, by = blockIdx.y*32;
  size_t base = (size_t)blockIdx.z * R * C;
  const unsigned short* src = (const unsigned short*)in + base;
  unsigned short* dst = (unsigned short*)out + base;
  int x = threadIdx.x, y0 = threadIdx.y;
#pragma unroll
  for (int i=0;i<4;i++){ int r = y0 + i*8; tile[r][x] = src[(size_t)(by+r)*C + bx + x]; }
  __syncthreads();
#pragma unroll
  for (int i=0;i<4;i++){ int c = y0 + i*8; dst[(size_t)(bx+c)*R + by + x] = tile[x][c]; }
}

// ---------------- RMSNorm fp32 -> bf16 ----------------
__global__ __launch_bounds__(256) void k_rmsnorm(const float* __restrict__ x, const float* __restrict__ w, bf16* __restrict__ out){
  int row = blockIdx.x, t = threadIdx.x;
  const float4 v = ((const float4*)(x + (size_t)row*DIM))[t];
  float ss = v.x*v.x + v.y*v.y + v.z*v.z + v.w*v.w;
#pragma unroll
  for (int m=1;m<64;m<<=1) ss += __shfl_xor(ss, m);
  __shared__ float red[4];
  if ((t&63)==0) red[t>>6] = ss;
  __syncthreads();
  float tot = red[0]+red[1]+red[2]+red[3];
  float r = rsqrtf(tot * (1.0f/DIM) + 1e-6f);
  const float4 wv = ((const float4*)w)[t];
  ushort4 o;
  o.x = f2b(v.x*r*wv.x); o.y = f2b(v.y*r*wv.y); o.z = f2b(v.z*r*wv.z); o.w = f2b(v.w*r*wv.w);
  ((ushort4*)(out + (size_t)row*DIM))[t] = o;
}

// ---------------- MFMA GEMM (m97-style global_load_lds staging) ----------------
// A[M x K] row-major, Bt[N x K] row-major.
// MODE 0: C bf16            MODE 1: C fp32 = acc + resid
// MODE 2: per-expert B (tile map), C bf16
// MODE 3: per-expert B (tile map), scatter to ybuf[slot][tok][col] = acc*w
#define BM 128
#define BN 128
#define BK 32

template<int MODE>
__global__ __launch_bounds__(256) void k_gemm(
    const bf16* __restrict__ A, const bf16* __restrict__ Bt,
    bf16* __restrict__ Cb, float* __restrict__ Cf, const float* __restrict__ resid,
    const int* __restrict__ tile_expert, const int* __restrict__ row_tok,
    const float* __restrict__ row_w, const int* __restrict__ row_slot,
    int N, int K)
{
  int tn = blockIdx.x, tm = blockIdx.y;
  int e = 0;
  if constexpr (MODE >= 2){ e = tile_expert[tm]; if (e < 0) return; }
  const bf16* Ablk = A + (size_t)tm*BM*K;
  const bf16* Bblk = Bt + ((MODE>=2) ? (size_t)e*N*K : (size_t)0) + (size_t)tn*BN*K;

  __shared__ bf16 lA[BM*BK];   // [128 rows][32 k], linear, 64B rows
  __shared__ bf16 lB[BN*BK];

  int t = threadIdx.x;
  int lane = t & 63, wave = t >> 6;
  int wr = wave >> 1, wc = wave & 1;
  int lr = lane & 15, lg = lane >> 4;

  // staging: each wave owns 32 rows of A and B; 2 calls each (16 rows/call,
  // 4 lanes per row x 16B). LDS dest = wave-uniform base + lane*16 (linear).
  int srow = wave*32 + (lane >> 2);
  int scol = (lane & 3) * 8;            // bf16 elements

  f32x4 acc[4][4] = {};

  for (int k0 = 0; k0 < K; k0 += BK){
    __syncthreads();                    // previous tile's reads complete
    lds16(Ablk + (size_t)srow*K        + k0 + scol, lA + wave*1024);
    lds16(Ablk + (size_t)(srow+16)*K   + k0 + scol, lA + wave*1024 + 512);
    lds16(Bblk + (size_t)srow*K        + k0 + scol, lB + wave*1024);
    lds16(Bblk + (size_t)(srow+16)*K   + k0 + scol, lB + wave*1024 + 512);
    __syncthreads();                    // drains vmcnt -> LDS ready
    bf16x8 af[4], bfv[4];
#pragma unroll
    for (int m=0;m<4;m++) af[m]  = *(const bf16x8*)(lA + (wr*64 + m*16 + lr)*BK + lg*8);
#pragma unroll
    for (int n=0;n<4;n++) bfv[n] = *(const bf16x8*)(lB + (wc*64 + n*16 + lr)*BK + lg*8);
#pragma unroll
    for (int m=0;m<4;m++)
#pragma unroll
      for (int n=0;n<4;n++)
        acc[m][n] = __builtin_amdgcn_mfma_f32_16x16x32_bf16(af[m], bfv[n], acc[m][n], 0, 0, 0);
  }

#pragma unroll
  for (int m=0;m<4;m++){
#pragma unroll
    for (int n=0;n<4;n++){
      int col = tn*BN + wc*64 + n*16 + lr;
#pragma unroll
      for (int j=0;j<4;j++){
        int row = tm*BM + wr*64 + m*16 + lg*4 + j;
        float v = acc[m][n][j];
        if constexpr (MODE==0 || MODE==2){
          Cb[(size_t)row*N + col] = __float2bfloat16(v);
        } else if constexpr (MODE==1){
          Cf[(size_t)row*N + col] = v + resid[(size_t)row*N + col];
        } else {
          int tok = row_tok[row];
          if (tok >= 0) Cf[((size_t)row_slot[row]*NTOK + tok)*DIM + col] = v * row_w[row];
        }
      }
    }
  }
}

// ---------------- RoPE + reshape qkv[T][1536] -> qr[B,H,S,HD], kr/vr[B,KV,S,HD] ----------------
__global__ __launch_bounds__(64) void k_rope(const bf16* __restrict__ qkv, const int* __restrict__ pos_ids,
    bf16* __restrict__ qr, bf16* __restrict__ kr, bf16* __restrict__ vr){
  int tk = blockIdx.x;
  int b = tk >> 10, s = tk & 1023;
  int d = threadIdx.x;
  float p = (float)pos_ids[tk];
  int i = d & 31;
  float freq = p * powf(10000.0f, -(float)(2*i)*(1.0f/HDIM));
  float sn, cs;
  sincosf(freq, &sn, &cs);
  const bf16* row = qkv + (size_t)tk*1536;
#pragma unroll
  for (int h=0; h<NH; h++){
    float x  = __bfloat162float(row[h*64 + d]);
    float xp = __bfloat162float(row[h*64 + ((d+32)&63)]);
    float rh = (d<32) ? -xp : xp;
    qr[(((size_t)(b*NH+h)*SEQ)+s)*HDIM + d] = __float2bfloat16(x*cs + rh*sn);
  }
#pragma unroll
  for (int h=0; h<NKV; h++){
    float x  = __bfloat162float(row[1024 + h*64 + d]);
    float xp = __bfloat162float(row[1024 + h*64 + ((d+32)&63)]);
    float rh = (d<32) ? -xp : xp;
    kr[(((size_t)(b*NKV+h)*SEQ)+s)*HDIM + d] = __float2bfloat16(x*cs + rh*sn);
    vr[(((size_t)(b*NKV+h)*SEQ)+s)*HDIM + d] = row[1280 + h*64 + d];
  }
}

// ---------------- MFMA flash attention ----------------
__global__ __launch_bounds__(64) void k_attn_mfma(const bf16* __restrict__ qr, const bf16* __restrict__ kr,
    const bf16* __restrict__ vT, bf16* __restrict__ out){
  int qt = blockIdx.x, h = blockIdx.y, b = blockIdx.z;
  int lane = threadIdx.x;
  int g = lane >> 4, c = lane & 15;
  int kv = h >> 2;
  int qbase = qt*16;
  const bf16* Qb = qr + (((size_t)(b*NH+h)*SEQ) + qbase)*HDIM;
  const bf16* Kb = kr + ((size_t)(b*NKV+kv)*SEQ)*HDIM;
  const bf16* Vt = vT + ((size_t)(b*NKV+kv)*HDIM)*SEQ;

  bf16x8 qa[2];
  qa[0] = *(const bf16x8*)(Qb + (size_t)c*HDIM + g*8);
  qa[1] = *(const bf16x8*)(Qb + (size_t)c*HDIM + 32 + g*8);

  f32x4 acc[4] = {};
  float m[4], l[4];
#pragma unroll
  for (int j=0;j<4;j++){ m[j] = -1e30f; l[j] = 0.f; }

  __shared__ bf16 P[16][40];

  int kend = qbase + 15;
  for (int k0 = 0; k0 <= kend; k0 += 32){
    f32x4 s[2] = {};
#pragma unroll
    for (int cn=0;cn<2;cn++){
#pragma unroll
      for (int dk=0;dk<2;dk++){
        bf16x8 kb = *(const bf16x8*)(Kb + (size_t)(k0+cn*16+c)*HDIM + dk*32 + g*8);
        s[cn] = __builtin_amdgcn_mfma_f32_16x16x32_bf16(qa[dk], kb, s[cn], 0, 0, 0);
      }
    }
    float sv[2][4];
    bool boundary = (k0 + 31 > qbase);
#pragma unroll
    for (int cn=0;cn<2;cn++){
#pragma unroll
      for (int j=0;j<4;j++){
        float v = s[cn][j] * 0.125f;
        if (boundary){
          int cg = k0 + cn*16 + c, rg = qbase + g*4 + j;
          if (cg > rg) v = -1e30f;
        }
        sv[cn][j] = v;
      }
    }
#pragma unroll
    for (int j=0;j<4;j++){
      float rmax = fmaxf(sv[0][j], sv[1][j]);
#pragma unroll
      for (int mk=1;mk<16;mk<<=1) rmax = fmaxf(rmax, __shfl_xor(rmax, mk));
      float mn = fmaxf(m[j], rmax);
      float corr = __expf(m[j] - mn);
      m[j] = mn;
      float p0 = __expf(sv[0][j] - mn);
      float p1 = __expf(sv[1][j] - mn);
      float rs = p0 + p1;
#pragma unroll
      for (int mk=1;mk<16;mk<<=1) rs += __shfl_xor(rs, mk);
      l[j] = l[j]*corr + rs;
#pragma unroll
      for (int db=0;db<4;db++) acc[db][j] *= corr;
      P[g*4+j][c]      = __float2bfloat16(p0);
      P[g*4+j][16+c]   = __float2bfloat16(p1);
    }
    __syncthreads();
    bf16x8 pa = *(const bf16x8*)(&P[c][g*8]);
#pragma unroll
    for (int db=0;db<4;db++){
      bf16x8 vb = *(const bf16x8*)(Vt + (size_t)(db*16+c)*SEQ + k0 + g*8);
      acc[db] = __builtin_amdgcn_mfma_f32_16x16x32_bf16(pa, vb, acc[db], 0, 0, 0);
    }
    __syncthreads();
  }
#pragma unroll
  for (int j=0;j<4;j++){
    float inv = 1.f / l[j];
    size_t rowoff = (size_t)(b*SEQ + qbase + g*4 + j)*1024 + h*64;
#pragma unroll
    for (int db=0;db<4;db++)
      out[rowoff + db*16 + c] = __float2bfloat16(acc[db][j] * inv);
  }
}

// ---------------- router: fp32 RMS-norm + logits + softmax + top-2 ----------------
__global__ __launch_bounds__(64) void k_router(const float* __restrict__ h1, const float* __restrict__ ln2w,
    const float* __restrict__ gw, float* __restrict__ scores,
    int* __restrict__ top_e, float* __restrict__ top_w, int* __restrict__ cnt){
  int tk = blockIdx.x, lane = threadIdx.x;
  const float* xr = h1 + (size_t)tk*DIM;
  const float4* x4 = (const float4*)xr;
  float4 xv[4];
  float ss = 0.f;
#pragma unroll
  for (int i=0;i<4;i++){
    xv[i] = x4[lane*4+i];
    ss += xv[i].x*xv[i].x + xv[i].y*xv[i].y + xv[i].z*xv[i].z + xv[i].w*xv[i].w;
  }
#pragma unroll
  for (int mm=1;mm<64;mm<<=1) ss += __shfl_xor(ss, mm);
  float r = rsqrtf(ss*(1.0f/DIM) + 1e-6f);
  float acc[8] = {0,0,0,0,0,0,0,0};
#pragma unroll
  for (int i=0;i<16;i++){
    int d = lane*16 + i;
    float xd = ((const float*)xv)[i];
    float xn = xd * r * ln2w[d];
    const float* g = gw + (size_t)d*NE;
#pragma unroll
    for (int e=0;e<8;e++) acc[e] += xn * g[e];
  }
#pragma unroll
  for (int e=0;e<8;e++){
#pragma unroll
    for (int mm=1;mm<64;mm<<=1) acc[e] += __shfl_xor(acc[e], mm);
  }
  float mx = acc[0];
#pragma unroll
  for (int e=1;e<8;e++) mx = fmaxf(mx, acc[e]);
  float w[8]; float se = 0.f;
#pragma unroll
  for (int e=0;e<8;e++){ w[e] = expf(acc[e]-mx); se += w[e]; }
  float inv = 1.f/se;
#pragma unroll
  for (int e=0;e<8;e++) w[e] *= inv;
  if (lane < 8) scores[(size_t)tk*NE + lane] = w[lane];
  if (lane == 0){
    int e1=0; float m1=w[0];
#pragma unroll
    for (int i=1;i<8;i++) if (w[i] > m1){ m1=w[i]; e1=i; }
    int e2=-1; float m2=-1.f;
#pragma unroll
    for (int i=0;i<8;i++) if (i!=e1 && w[i] > m2){ m2=w[i]; e2=i; }
    float s12 = m1 + m2;
    top_e[2*tk] = e1;   top_w[2*tk]   = m1/s12;
    top_e[2*tk+1] = e2; top_w[2*tk+1] = m2/s12;
    atomicAdd(&cnt[e1], 1); atomicAdd(&cnt[e2], 1);
  }
}

// ---------------- 128-aligned segment offsets + tile->expert map ----------------
__global__ __launch_bounds__(256) void k_offsets(const int* __restrict__ cnt, int* __restrict__ seg_off,
    int* __restrict__ tile_expert, int* __restrict__ row_tok){
  int t = threadIdx.x;
  for (int i=t;i<MAXR;i+=256) row_tok[i] = -1;
  for (int i=t;i<MAXTILES;i+=256) tile_expert[i] = -1;
  __syncthreads();
  if (t == 0){
    int off = 0;
    for (int e=0;e<NE;e++){
      seg_off[e] = off;
      int nt = (cnt[e] + 127) >> 7;
      for (int i=0;i<nt;i++) tile_expert[(off>>7)+i] = e;
      off += nt << 7;
    }
  }
}

// ---------------- scatter token pairs into expert segments ----------------
__global__ __launch_bounds__(256) void k_scatter(const int* __restrict__ top_e, const float* __restrict__ top_w,
    const int* __restrict__ seg_off, int* __restrict__ cnt2,
    int* __restrict__ row_tok, float* __restrict__ row_w, int* __restrict__ row_slot){
  int tkn = blockIdx.x*256 + threadIdx.x;
  if (tkn >= NTOK) return;
#pragma unroll
  for (int k=0;k<2;k++){
    int e = top_e[2*tkn+k];
    int p = atomicAdd(&cnt2[e], 1);
    int r = seg_off[e] + p;
    row_tok[r] = tkn; row_w[r] = top_w[2*tkn+k]; row_slot[r] = k;
  }
}

// ---------------- gather xn2 rows into compacted Xg ----------------
__global__ __launch_bounds__(256) void k_gather(const int* __restrict__ row_tok, const bf16* __restrict__ xn,
    bf16* __restrict__ Xg){
  int r = blockIdx.x, t = threadIdx.x;
  int tok = row_tok[r];
  ushort4* dst = (ushort4*)(Xg + (size_t)r*DIM) + t;
  if (tok < 0){ ushort4 z; z.x=0; z.y=0; z.z=0; z.w=0; *dst = z; }
  else *dst = ((const ushort4*)(xn + (size_t)tok*DIM))[t];
}

// ---------------- h = silu(a) * b from fused h13 ----------------
__global__ __launch_bounds__(256) void k_silumul(const bf16* __restrict__ h13, bf16* __restrict__ o){
  size_t i = (size_t)blockIdx.x*256 + threadIdx.x;
  size_t r = i >> 9;             // NF/4 = 512 quads per row
  int fq = (int)(i & 511);
  const bf16* rowp = h13 + r*(2*NF);
  ushort4 ua = ((const ushort4*)rowp)[fq];
  ushort4 ub = ((const ushort4*)(rowp + NF))[fq];
  ushort4 uo;
  { float fa=b2f(ua.x), fb=b2f(ub.x); uo.x = f2b(fa/(1.f+__expf(-fa))*fb); }
  { float fa=b2f(ua.y), fb=b2f(ub.y); uo.y = f2b(fa/(1.f+__expf(-fa))*fb); }
  { float fa=b2f(ua.z), fb=b2f(ub.z); uo.z = f2b(fa/(1.f+__expf(-fa))*fb); }
  { float fa=b2f(ua.w), fb=b2f(ub.w); uo.w = f2b(fa/(1.f+__expf(-fa))*fb); }
  ((ushort4*)(o))[i] = uo;
}

// ---------------- out = h1 + ybuf0 + ybuf1 ----------------
__global__ __launch_bounds__(256) void k_final(const float* __restrict__ h1, const float* __restrict__ ybuf, float* __restrict__ out){
  size_t i = (size_t)blockIdx.x*256 + threadIdx.x;
  float4 a  = ((const float4*)h1)[i];
  float4 b0 = ((const float4*)ybuf)[i];
  float4 b1 = ((const float4*)(ybuf + (size_t)NTOK*DIM))[i];
  float4 r;
  r.x = a.x+b0.x+b1.x; r.y = a.y+b0.y+b1.y; r.z = a.z+b0.z+b1.z; r.w = a.w+b0.w+b1.w;
  ((float4*)out)[i] = r;
}

extern "C" void kernel_launch(void* const* d_in, const int* in_sizes, int n_in,
                              void* d_out, int out_size, void* d_ws, size_t ws_size,
                              hipStream_t stream){
  const float* hidden = (const float*)d_in[0];
  const int*   pos    = (const int*)d_in[1];
  const float* ln1    = (const float*)d_in[3];
  const float* ln2    = (const float*)d_in[4];
  const float* wq     = (const float*)d_in[5];
  const float* wk     = (const float*)d_in[6];
  const float* wv     = (const float*)d_in[7];
  const float* wo     = (const float*)d_in[8];
  const float* gw     = (const float*)d_in[9];
  const float* w1     = (const float*)d_in[10];
  const float* w3     = (const float*)d_in[11];
  const float* w2     = (const float*)d_in[12];
  float* out1 = (float*)d_out;
  float* out2 = out1 + (size_t)NTOK*DIM;

  char* p = (char*)d_ws;
  auto take = [&](size_t bytes){ void* r = (void*)p; p += (bytes + 255) & ~(size_t)255; return r; };
  bf16* wqkvT = (bf16*)take((size_t)1536*1024*2);
  bf16* woT   = (bf16*)take((size_t)1024*1024*2);
  bf16* w13T  = (bf16*)take((size_t)NE*2*NF*DIM*2);   // [e][4096][1024]: rows 0-2047=w1T, 2048-4095=w3T
  bf16* w2T   = (bf16*)take((size_t)NE*DIM*NF*2);
  float* h1   = (float*)take((size_t)NTOK*DIM*4);
  bf16* xn2   = (bf16*)take((size_t)NTOK*DIM*2);
  int*  cnt   = (int*)take(64);          // cnt[8] then cnt2[8]
  int*  cnt2  = cnt + 8;
  int*  seg_off     = (int*)take(64);
  int*  tile_expert = (int*)take(MAXTILES*4);
  int*  top_e  = (int*)take((size_t)NTOK*2*4);
  float* top_w = (float*)take((size_t)NTOK*2*4);
  int*  row_tok  = (int*)take((size_t)MAXR*4);
  float* row_w   = (float*)take((size_t)MAXR*4);
  int*  row_slot = (int*)take((size_t)MAXR*4);
  bf16* Xg     = (bf16*)take((size_t)MAXR*DIM*2);
  bf16* h13buf = (bf16*)take((size_t)MAXR*2*NF*2);    // [r][4096]
  bf16* hbuf   = (bf16*)take((size_t)MAXR*NF*2);
  // region A overlays Xg+h13buf head (50MB window); all dead before Xg/h13buf written
  char* ra = (char*)Xg;
  bf16* xn1 = (bf16*)ra;       ra += (size_t)NTOK*DIM*2;
  bf16* qkv = (bf16*)ra;       ra += (size_t)NTOK*1536*2;
  bf16* qr  = (bf16*)ra;       ra += (size_t)NTOK*DIM*2;
  bf16* krp = (bf16*)ra;       ra += (size_t)NTOK*NKV*HDIM*2; // 1MB
  bf16* vrp = (bf16*)ra;       ra += (size_t)NTOK*NKV*HDIM*2;
  bf16* vTp = (bf16*)ra;       ra += (size_t)NTOK*NKV*HDIM*2; // [B*KV][HD][S]
  bf16* attn_out = (bf16*)ra;  ra += (size_t)NTOK*DIM*2;
  float* ybuf = (float*)h13buf; // [2][NTOK][DIM] fp32 (16MB <= 40MB), h13buf dead by then

  // 0) zero counters
  k_zero_i32<<<dim3(1), dim3(256), 0, stream>>>(cnt, 16);
  // 1) weight transposes (fp32 -> bf16, B^T layout)
  k_transpose<<<dim3(32,32,1), dim3(32,8), 0, stream>>>(wq, wqkvT, 1024, 1024, (size_t)1024*1024, (size_t)1024*1024);
  k_transpose<<<dim3(8,32,1),  dim3(32,8), 0, stream>>>(wk, wqkvT + (size_t)1024*1024, 1024, 256, (size_t)1024*256, (size_t)1024*256);
  k_transpose<<<dim3(8,32,1),  dim3(32,8), 0, stream>>>(wv, wqkvT + (size_t)1280*1024, 1024, 256, (size_t)1024*256, (size_t)1024*256);
  k_transpose<<<dim3(32,32,1), dim3(32,8), 0, stream>>>(wo, woT, 1024, 1024, (size_t)1024*1024, (size_t)1024*1024);
  k_transpose<<<dim3(NF/32, DIM/32, NE), dim3(32,8), 0, stream>>>(w1, w13T, DIM, NF, (size_t)DIM*NF, (size_t)2*NF*DIM);
  k_transpose<<<dim3(NF/32, DIM/32, NE), dim3(32,8), 0, stream>>>(w3, w13T + (size_t)NF*DIM, DIM, NF, (size_t)DIM*NF, (size_t)2*NF*DIM);
  k_transpose<<<dim3(DIM/32, NF/32, NE), dim3(32,8), 0, stream>>>(w2, w2T, NF, DIM, (size_t)NF*DIM, (size_t)NF*DIM);
  // 2) ln1
  k_rmsnorm<<<dim3(NTOK), dim3(256), 0, stream>>>(hidden, ln1, xn1);
  // 3) qkv projection
  k_gemm<0><<<dim3(1536/BN, NTOK/BM), dim3(256), 0, stream>>>(xn1, wqkvT, qkv, nullptr, nullptr, nullptr, nullptr, nullptr, nullptr, 1536, 1024);
  // 4) rope + reshape
  k_rope<<<dim3(NTOK), dim3(64), 0, stream>>>(qkv, pos, qr, krp, vrp);
  // 4b) V transpose -> [d][s]
  k_tbf<<<dim3(HDIM/32, SEQ/32, 2*NKV), dim3(32,8), 0, stream>>>(vrp, vTp, SEQ, HDIM);
  // 5) attention (MFMA flash)
  k_attn_mfma<<<dim3(SEQ/16, NH, 2), dim3(64), 0, stream>>>(qr, krp, vTp, attn_out);
  // 6) o-proj + residual -> h1 (fp32)
  k_gemm<1><<<dim3(DIM/BN, NTOK/BM), dim3(256), 0, stream>>>(attn_out, woT, nullptr, h1, hidden, nullptr, nullptr, nullptr, nullptr, DIM, 1024);
  // 7) ln2 (bf16 xn2 for expert inputs; router reads fp32 h1)
  k_rmsnorm<<<dim3(NTOK), dim3(256), 0, stream>>>(h1, ln2, xn2);
  // 8) router (fp32-exact routing; writes gate_scores output)
  k_router<<<dim3(NTOK), dim3(64), 0, stream>>>(h1, ln2, gw, out2, top_e, top_w, cnt);
  // 9) segment offsets + tile map
  k_offsets<<<dim3(1), dim3(256), 0, stream>>>(cnt, seg_off, tile_expert, row_tok);
  // 10) scatter pairs
  k_scatter<<<dim3(NTOK/256), dim3(256), 0, stream>>>(top_e, top_w, seg_off, cnt2, row_tok, row_w, row_slot);
  // 11) gather rows
  k_gather<<<dim3(MAXR), dim3(256), 0, stream>>>(row_tok, xn2, Xg);
  // 12) fused expert GEMM1 (w1|w3 stacked, N=4096)
  k_gemm<2><<<dim3(2*NF/BN, MAXTILES), dim3(256), 0, stream>>>(Xg, w13T, h13buf, nullptr, nullptr, tile_expert, nullptr, nullptr, nullptr, 2*NF, DIM);
  // 13) swiglu from fused halves
  k_silumul<<<dim3((unsigned)((size_t)MAXR*NF/4/256)), dim3(256), 0, stream>>>(h13buf, hbuf);
  // 14) expert GEMM2 -> ybuf (weighted, scattered)
  k_gemm<3><<<dim3(DIM/BN, MAXTILES), dim3(256), 0, stream>>>(hbuf, w2T, nullptr, ybuf, nullptr, tile_expert, row_tok, row_w, row_slot, DIM, NF);
  // 15) final residual add
  k_final<<<dim3(NTOK*DIM/4/256), dim3(256), 0, stream>>>(h1, ybuf, out1);
}

// Round 6
// 563.493 us; speedup vs baseline: 2.7978x; 1.0950x over previous
//
#include <hip/hip_runtime.h>
#include <hip/hip_bf16.h>
#include <stdint.h>

using bf16 = __hip_bfloat16;
using bf16x8 = __attribute__((ext_vector_type(8))) __bf16;
using f32x4  = __attribute__((ext_vector_type(4))) float;

#define NTOK 2048
#define DIM 1024
#define NH 16
#define NKV 4
#define HDIM 64
#define NE 8
#define NF 2048
#define SEQ 1024
#define MAXR 5120      // 4096 pairs + 8*128 alignment slack
#define MAXTILES 40

__device__ __forceinline__ float b2f(unsigned short u){ unsigned v=((unsigned)u)<<16; float f; __builtin_memcpy(&f,&v,4); return f; }
__device__ __forceinline__ unsigned short f2b(float f){ bf16 h=__float2bfloat16(f); unsigned short u; __builtin_memcpy(&u,&h,2); return u; }

typedef __attribute__((address_space(3))) unsigned int lds_u32;
typedef const __attribute__((address_space(1))) unsigned int glb_u32;
__device__ __forceinline__ void lds16(const void* g, void* l){
  __builtin_amdgcn_global_load_lds((glb_u32*)g, (lds_u32*)l, 16, 0, 0);
}

// ---------------- zero small int buffers ----------------
__global__ void k_zero_i32(int* p, int n){ int i=blockIdx.x*256+threadIdx.x; if(i<n) p[i]=0; }

// ---------------- transpose+cast: fp32 [Z][R][C] -> bf16 [Z][C][R] ----------------
__global__ __launch_bounds__(256) void k_transpose(const float* __restrict__ in, bf16* __restrict__ out,
    int R, int C, size_t inz, size_t outz){
  __shared__ float tile[32][33];
  int bx = blockIdx.x*32, by = blockIdx.y*32;
  const float* src = in + (size_t)blockIdx.z * inz;
  bf16* dst = out + (size_t)blockIdx.z * outz;
  int x = threadIdx.x, y0 = threadIdx.y;
#pragma unroll
  for (int i=0;i<4;i++){ int r = y0 + i*8; tile[r][x] = src[(size_t)(by+r)*C + bx + x]; }
  __syncthreads();
#pragma unroll
  for (int i=0;i<4;i++){ int c = y0 + i*8; dst[(size_t)(bx+c)*R + by + x] = __float2bfloat16(tile[x][c]); }
}

// ---------------- bf16 transpose: [Z][R][C] -> [Z][C][R] ----------------
__global__ __launch_bounds__(256) void k_tbf(const bf16* __restrict__ in, bf16* __restrict__ out, int R, int C){
  __shared__ unsigned short tile[32][33];
  int bx = blockIdx.x*32, by = blockIdx.y*32;
  size_t base = (size_t)blockIdx.z * R * C;
  const unsigned short* src = (const unsigned short*)in + base;
  unsigned short* dst = (unsigned short*)out + base;
  int x = threadIdx.x, y0 = threadIdx.y;
#pragma unroll
  for (int i=0;i<4;i++){ int r = y0 + i*8; tile[r][x] = src[(size_t)(by+r)*C + bx + x]; }
  __syncthreads();
#pragma unroll
  for (int i=0;i<4;i++){ int c = y0 + i*8; dst[(size_t)(bx+c)*R + by + x] = tile[x][c]; }
}

// ---------------- RMSNorm fp32 -> bf16 (ln1 only) ----------------
__global__ __launch_bounds__(256) void k_rmsnorm(const float* __restrict__ x, const float* __restrict__ w, bf16* __restrict__ out){
  int row = blockIdx.x, t = threadIdx.x;
  const float4 v = ((const float4*)(x + (size_t)row*DIM))[t];
  float ss = v.x*v.x + v.y*v.y + v.z*v.z + v.w*v.w;
#pragma unroll
  for (int m=1;m<64;m<<=1) ss += __shfl_xor(ss, m);
  __shared__ float red[4];
  if ((t&63)==0) red[t>>6] = ss;
  __syncthreads();
  float tot = red[0]+red[1]+red[2]+red[3];
  float r = rsqrtf(tot * (1.0f/DIM) + 1e-6f);
  const float4 wv = ((const float4*)w)[t];
  ushort4 o;
  o.x = f2b(v.x*r*wv.x); o.y = f2b(v.y*r*wv.y); o.z = f2b(v.z*r*wv.z); o.w = f2b(v.w*r*wv.w);
  ((ushort4*)(out + (size_t)row*DIM))[t] = o;
}

// ---------------- MFMA GEMM: BK=64, XOR slot-swizzled LDS, gload_lds staging ----
// A[M x K] row-major, Bt[N x K] row-major. BMT in {64,128}, BN=128.
// MODE 0: C bf16            MODE 1: C fp32 = acc + resid
// MODE 2: per-expert B (tile map), C bf16
// MODE 3: per-expert B (tile map), scatter to ybuf[slot][tok][col] = acc*w
#define BN 128
#define BK 64

template<int MODE, int BMT>
__global__ __launch_bounds__(256) void k_gemm(
    const bf16* __restrict__ A, const bf16* __restrict__ Bt,
    bf16* __restrict__ Cb, float* __restrict__ Cf, const float* __restrict__ resid,
    const int* __restrict__ tile_expert, const int* __restrict__ row_tok,
    const float* __restrict__ row_w, const int* __restrict__ row_slot,
    int N, int K)
{
  int tn = blockIdx.x, tm = blockIdx.y;
  int e = 0;
  if constexpr (MODE >= 2){ e = tile_expert[(tm*BMT)>>7]; if (e < 0) return; }
  const bf16* Ablk = A + (size_t)tm*BMT*K;
  const bf16* Bblk = Bt + ((MODE>=2) ? (size_t)e*N*K : (size_t)0) + (size_t)tn*BN*K;

  __shared__ bf16 lA[BMT*BK];   // rows of 128B, 8 slots of 16B, slot-swizzled
  __shared__ bf16 lB[BN*BK];

  int t = threadIdx.x;
  int lane = t & 63, wave = t >> 6;
  int wr = wave >> 1, wc = wave & 1;
  int lr = lane & 15, lg = lane >> 4;

  // staging: each lds16 call fills 8 rows x 128B linearly; lane -> (row=lane>>3,
  // stored slot=lane&7). Stored slot s holds logical slot s ^ (row&7), so the
  // global source column is pre-swizzled (dest must stay linear for gload_lds).
  int sln  = lane >> 3;                         // row within 8-row chunk == row&7
  int scol = ((lane & 7) ^ sln) * 8;            // bf16 elements within BK
  constexpr int AR = BMT/4;                     // A rows per wave
  int sArow = wave*AR + sln;
  int sBrow = wave*32 + sln;

  constexpr int MF = BMT/32;                    // m-frags per wave
  f32x4 acc[MF][4] = {};

  int swz = lr & 7;                             // read-side row&7

  for (int k0 = 0; k0 < K; k0 += BK){
    __syncthreads();                            // prior reads done before overwrite
#pragma unroll
    for (int ch = 0; ch < AR/8; ch++)
      lds16(Ablk + (size_t)(sArow + ch*8)*K + k0 + scol, lA + (wave*AR + ch*8)*BK);
#pragma unroll
    for (int ch = 0; ch < 4; ch++)
      lds16(Bblk + (size_t)(sBrow + ch*8)*K + k0 + scol, lB + (wave*32 + ch*8)*BK);
    __syncthreads();                            // drains vmcnt -> LDS ready
#pragma unroll
    for (int kk = 0; kk < 2; kk++){
      bf16x8 af[MF], bfv[4];
#pragma unroll
      for (int m=0;m<MF;m++){
        int R = wr*(BMT/2) + m*16 + lr;
        af[m] = *(const bf16x8*)(lA + R*BK + ((((kk<<2)|lg) ^ swz)<<3));
      }
#pragma unroll
      for (int n=0;n<4;n++){
        int R = wc*64 + n*16 + lr;
        bfv[n] = *(const bf16x8*)(lB + R*BK + ((((kk<<2)|lg) ^ swz)<<3));
      }
#pragma unroll
      for (int m=0;m<MF;m++)
#pragma unroll
        for (int n=0;n<4;n++)
          acc[m][n] = __builtin_amdgcn_mfma_f32_16x16x32_bf16(af[m], bfv[n], acc[m][n], 0, 0, 0);
    }
  }

#pragma unroll
  for (int m=0;m<MF;m++){
#pragma unroll
    for (int n=0;n<4;n++){
      int col = tn*BN + wc*64 + n*16 + lr;
#pragma unroll
      for (int j=0;j<4;j++){
        int row = tm*BMT + wr*(BMT/2) + m*16 + lg*4 + j;
        float v = acc[m][n][j];
        if constexpr (MODE==0 || MODE==2){
          Cb[(size_t)row*N + col] = __float2bfloat16(v);
        } else if constexpr (MODE==1){
          Cf[(size_t)row*N + col] = v + resid[(size_t)row*N + col];
        } else {
          int tok = row_tok[row];
          if (tok >= 0) Cf[((size_t)row_slot[row]*NTOK + tok)*DIM + col] = v * row_w[row];
        }
      }
    }
  }
}

// ---------------- RoPE + reshape qkv[T][1536] -> qr[B,H,S,HD], kr/vr[B,KV,S,HD] ----------------
__global__ __launch_bounds__(64) void k_rope(const bf16* __restrict__ qkv, const int* __restrict__ pos_ids,
    bf16* __restrict__ qr, bf16* __restrict__ kr, bf16* __restrict__ vr){
  int tk = blockIdx.x;
  int b = tk >> 10, s = tk & 1023;
  int d = threadIdx.x;
  float p = (float)pos_ids[tk];
  int i = d & 31;
  float freq = p * powf(10000.0f, -(float)(2*i)*(1.0f/HDIM));
  float sn, cs;
  sincosf(freq, &sn, &cs);
  const bf16* row = qkv + (size_t)tk*1536;
#pragma unroll
  for (int h=0; h<NH; h++){
    float x  = __bfloat162float(row[h*64 + d]);
    float xp = __bfloat162float(row[h*64 + ((d+32)&63)]);
    float rh = (d<32) ? -xp : xp;
    qr[(((size_t)(b*NH+h)*SEQ)+s)*HDIM + d] = __float2bfloat16(x*cs + rh*sn);
  }
#pragma unroll
  for (int h=0; h<NKV; h++){
    float x  = __bfloat162float(row[1024 + h*64 + d]);
    float xp = __bfloat162float(row[1024 + h*64 + ((d+32)&63)]);
    float rh = (d<32) ? -xp : xp;
    kr[(((size_t)(b*NKV+h)*SEQ)+s)*HDIM + d] = __float2bfloat16(x*cs + rh*sn);
    vr[(((size_t)(b*NKV+h)*SEQ)+s)*HDIM + d] = row[1280 + h*64 + d];
  }
}

// ---------------- MFMA flash attention ----------------
__global__ __launch_bounds__(64) void k_attn_mfma(const bf16* __restrict__ qr, const bf16* __restrict__ kr,
    const bf16* __restrict__ vT, bf16* __restrict__ out){
  int qt = blockIdx.x, h = blockIdx.y, b = blockIdx.z;
  int lane = threadIdx.x;
  int g = lane >> 4, c = lane & 15;
  int kv = h >> 2;
  int qbase = qt*16;
  const bf16* Qb = qr + (((size_t)(b*NH+h)*SEQ) + qbase)*HDIM;
  const bf16* Kb = kr + ((size_t)(b*NKV+kv)*SEQ)*HDIM;
  const bf16* Vt = vT + ((size_t)(b*NKV+kv)*HDIM)*SEQ;

  bf16x8 qa[2];
  qa[0] = *(const bf16x8*)(Qb + (size_t)c*HDIM + g*8);
  qa[1] = *(const bf16x8*)(Qb + (size_t)c*HDIM + 32 + g*8);

  f32x4 acc[4] = {};
  float m[4], l[4];
#pragma unroll
  for (int j=0;j<4;j++){ m[j] = -1e30f; l[j] = 0.f; }

  __shared__ bf16 P[16][40];

  int kend = qbase + 15;
  for (int k0 = 0; k0 <= kend; k0 += 32){
    f32x4 s[2] = {};
#pragma unroll
    for (int cn=0;cn<2;cn++){
#pragma unroll
      for (int dk=0;dk<2;dk++){
        bf16x8 kb = *(const bf16x8*)(Kb + (size_t)(k0+cn*16+c)*HDIM + dk*32 + g*8);
        s[cn] = __builtin_amdgcn_mfma_f32_16x16x32_bf16(qa[dk], kb, s[cn], 0, 0, 0);
      }
    }
    float sv[2][4];
    bool boundary = (k0 + 31 > qbase);
#pragma unroll
    for (int cn=0;cn<2;cn++){
#pragma unroll
      for (int j=0;j<4;j++){
        float v = s[cn][j] * 0.125f;
        if (boundary){
          int cg = k0 + cn*16 + c, rg = qbase + g*4 + j;
          if (cg > rg) v = -1e30f;
        }
        sv[cn][j] = v;
      }
    }
#pragma unroll
    for (int j=0;j<4;j++){
      float rmax = fmaxf(sv[0][j], sv[1][j]);
#pragma unroll
      for (int mk=1;mk<16;mk<<=1) rmax = fmaxf(rmax, __shfl_xor(rmax, mk));
      float mn = fmaxf(m[j], rmax);
      float corr = __expf(m[j] - mn);
      m[j] = mn;
      float p0 = __expf(sv[0][j] - mn);
      float p1 = __expf(sv[1][j] - mn);
      float rs = p0 + p1;
#pragma unroll
      for (int mk=1;mk<16;mk<<=1) rs += __shfl_xor(rs, mk);
      l[j] = l[j]*corr + rs;
#pragma unroll
      for (int db=0;db<4;db++) acc[db][j] *= corr;
      P[g*4+j][c]      = __float2bfloat16(p0);
      P[g*4+j][16+c]   = __float2bfloat16(p1);
    }
    __syncthreads();
    bf16x8 pa = *(const bf16x8*)(&P[c][g*8]);
#pragma unroll
    for (int db=0;db<4;db++){
      bf16x8 vb = *(const bf16x8*)(Vt + (size_t)(db*16+c)*SEQ + k0 + g*8);
      acc[db] = __builtin_amdgcn_mfma_f32_16x16x32_bf16(pa, vb, acc[db], 0, 0, 0);
    }
    __syncthreads();
  }
#pragma unroll
  for (int j=0;j<4;j++){
    float inv = 1.f / l[j];
    size_t rowoff = (size_t)(b*SEQ + qbase + g*4 + j)*1024 + h*64;
#pragma unroll
    for (int db=0;db<4;db++)
      out[rowoff + db*16 + c] = __float2bfloat16(acc[db][j] * inv);
  }
}

// ---------------- fused ln2-RMSNorm + router (fp32-exact) ----------------
// Writes bf16 xn2 (expert input) AND routing decisions in one pass over h1.
__global__ __launch_bounds__(64) void k_router(const float* __restrict__ h1, const float* __restrict__ ln2w,
    const float* __restrict__ gw, float* __restrict__ scores, bf16* __restrict__ xn2,
    int* __restrict__ top_e, float* __restrict__ top_w, int* __restrict__ cnt){
  int tk = blockIdx.x, lane = threadIdx.x;
  const float* xr = h1 + (size_t)tk*DIM;
  const float4* x4 = (const float4*)xr;
  float4 xv[4];
  float ss = 0.f;
#pragma unroll
  for (int i=0;i<4;i++){
    xv[i] = x4[lane*4+i];
    ss += xv[i].x*xv[i].x + xv[i].y*xv[i].y + xv[i].z*xv[i].z + xv[i].w*xv[i].w;
  }
#pragma unroll
  for (int mm=1;mm<64;mm<<=1) ss += __shfl_xor(ss, mm);
  float r = rsqrtf(ss*(1.0f/DIM) + 1e-6f);
  float acc[8] = {0,0,0,0,0,0,0,0};
  unsigned short xo[16];
#pragma unroll
  for (int i=0;i<16;i++){
    int d = lane*16 + i;
    float xd = ((const float*)xv)[i];
    float xn = xd * r * ln2w[d];
    xo[i] = f2b(xn);
    const float* g = gw + (size_t)d*NE;
#pragma unroll
    for (int e=0;e<8;e++) acc[e] += xn * g[e];
  }
#pragma unroll
  for (int i=0;i<4;i++)
    ((ushort4*)(xn2 + (size_t)tk*DIM + lane*16))[i] = *(ushort4*)(xo + i*4);
#pragma unroll
  for (int e=0;e<8;e++){
#pragma unroll
    for (int mm=1;mm<64;mm<<=1) acc[e] += __shfl_xor(acc[e], mm);
  }
  float mx = acc[0];
#pragma unroll
  for (int e=1;e<8;e++) mx = fmaxf(mx, acc[e]);
  float w[8]; float se = 0.f;
#pragma unroll
  for (int e=0;e<8;e++){ w[e] = expf(acc[e]-mx); se += w[e]; }
  float inv = 1.f/se;
#pragma unroll
  for (int e=0;e<8;e++) w[e] *= inv;
  if (lane < 8) scores[(size_t)tk*NE + lane] = w[lane];
  if (lane == 0){
    int e1=0; float m1=w[0];
#pragma unroll
    for (int i=1;i<8;i++) if (w[i] > m1){ m1=w[i]; e1=i; }
    int e2=-1; float m2=-1.f;
#pragma unroll
    for (int i=0;i<8;i++) if (i!=e1 && w[i] > m2){ m2=w[i]; e2=i; }
    float s12 = m1 + m2;
    top_e[2*tk] = e1;   top_w[2*tk]   = m1/s12;
    top_e[2*tk+1] = e2; top_w[2*tk+1] = m2/s12;
    atomicAdd(&cnt[e1], 1); atomicAdd(&cnt[e2], 1);
  }
}

// ---------------- 128-aligned segment offsets + tile->expert map ----------------
__global__ __launch_bounds__(256) void k_offsets(const int* __restrict__ cnt, int* __restrict__ seg_off,
    int* __restrict__ tile_expert, int* __restrict__ row_tok){
  int t = threadIdx.x;
  for (int i=t;i<MAXR;i+=256) row_tok[i] = -1;
  for (int i=t;i<MAXTILES;i+=256) tile_expert[i] = -1;
  __syncthreads();
  if (t == 0){
    int off = 0;
    for (int e=0;e<NE;e++){
      seg_off[e] = off;
      int nt = (cnt[e] + 127) >> 7;
      for (int i=0;i<nt;i++) tile_expert[(off>>7)+i] = e;
      off += nt << 7;
    }
  }
}

// ---------------- scatter token pairs into expert segments ----------------
__global__ __launch_bounds__(256) void k_scatter(const int* __restrict__ top_e, const float* __restrict__ top_w,
    const int* __restrict__ seg_off, int* __restrict__ cnt2,
    int* __restrict__ row_tok, float* __restrict__ row_w, int* __restrict__ row_slot){
  int tkn = blockIdx.x*256 + threadIdx.x;
  if (tkn >= NTOK) return;
#pragma unroll
  for (int k=0;k<2;k++){
    int e = top_e[2*tkn+k];
    int p = atomicAdd(&cnt2[e], 1);
    int r = seg_off[e] + p;
    row_tok[r] = tkn; row_w[r] = top_w[2*tkn+k]; row_slot[r] = k;
  }
}

// ---------------- gather xn2 rows into compacted Xg ----------------
__global__ __launch_bounds__(256) void k_gather(const int* __restrict__ row_tok, const bf16* __restrict__ xn,
    bf16* __restrict__ Xg){
  int r = blockIdx.x, t = threadIdx.x;
  int tok = row_tok[r];
  ushort4* dst = (ushort4*)(Xg + (size_t)r*DIM) + t;
  if (tok < 0){ ushort4 z; z.x=0; z.y=0; z.z=0; z.w=0; *dst = z; }
  else *dst = ((const ushort4*)(xn + (size_t)tok*DIM))[t];
}

// ---------------- h = silu(a) * b from fused h13 ----------------
__global__ __launch_bounds__(256) void k_silumul(const bf16* __restrict__ h13, bf16* __restrict__ o){
  size_t i = (size_t)blockIdx.x*256 + threadIdx.x;
  size_t r = i >> 9;             // NF/4 = 512 quads per row
  int fq = (int)(i & 511);
  const bf16* rowp = h13 + r*(2*NF);
  ushort4 ua = ((const ushort4*)rowp)[fq];
  ushort4 ub = ((const ushort4*)(rowp + NF))[fq];
  ushort4 uo;
  { float fa=b2f(ua.x), fb=b2f(ub.x); uo.x = f2b(fa/(1.f+__expf(-fa))*fb); }
  { float fa=b2f(ua.y), fb=b2f(ub.y); uo.y = f2b(fa/(1.f+__expf(-fa))*fb); }
  { float fa=b2f(ua.z), fb=b2f(ub.z); uo.z = f2b(fa/(1.f+__expf(-fa))*fb); }
  { float fa=b2f(ua.w), fb=b2f(ub.w); uo.w = f2b(fa/(1.f+__expf(-fa))*fb); }
  ((ushort4*)(o))[i] = uo;
}

// ---------------- out = h1 + ybuf0 + ybuf1 ----------------
__global__ __launch_bounds__(256) void k_final(const float* __restrict__ h1, const float* __restrict__ ybuf, float* __restrict__ out){
  size_t i = (size_t)blockIdx.x*256 + threadIdx.x;
  float4 a  = ((const float4*)h1)[i];
  float4 b0 = ((const float4*)ybuf)[i];
  float4 b1 = ((const float4*)(ybuf + (size_t)NTOK*DIM))[i];
  float4 r;
  r.x = a.x+b0.x+b1.x; r.y = a.y+b0.y+b1.y; r.z = a.z+b0.z+b1.z; r.w = a.w+b0.w+b1.w;
  ((float4*)out)[i] = r;
}

extern "C" void kernel_launch(void* const* d_in, const int* in_sizes, int n_in,
                              void* d_out, int out_size, void* d_ws, size_t ws_size,
                              hipStream_t stream){
  const float* hidden = (const float*)d_in[0];
  const int*   pos    = (const int*)d_in[1];
  const float* ln1    = (const float*)d_in[3];
  const float* ln2    = (const float*)d_in[4];
  const float* wq     = (const float*)d_in[5];
  const float* wk     = (const float*)d_in[6];
  const float* wv     = (const float*)d_in[7];
  const float* wo     = (const float*)d_in[8];
  const float* gw     = (const float*)d_in[9];
  const float* w1     = (const float*)d_in[10];
  const float* w3     = (const float*)d_in[11];
  const float* w2     = (const float*)d_in[12];
  float* out1 = (float*)d_out;
  float* out2 = out1 + (size_t)NTOK*DIM;

  char* p = (char*)d_ws;
  auto take = [&](size_t bytes){ void* r = (void*)p; p += (bytes + 255) & ~(size_t)255; return r; };
  bf16* wqkvT = (bf16*)take((size_t)1536*1024*2);
  bf16* woT   = (bf16*)take((size_t)1024*1024*2);
  bf16* w13T  = (bf16*)take((size_t)NE*2*NF*DIM*2);   // [e][4096][1024]: rows 0-2047=w1T, 2048-4095=w3T
  bf16* w2T   = (bf16*)take((size_t)NE*DIM*NF*2);
  float* h1   = (float*)take((size_t)NTOK*DIM*4);
  bf16* xn2   = (bf16*)take((size_t)NTOK*DIM*2);
  int*  cnt   = (int*)take(64);          // cnt[8] then cnt2[8]
  int*  cnt2  = cnt + 8;
  int*  seg_off     = (int*)take(64);
  int*  tile_expert = (int*)take(MAXTILES*4);
  int*  top_e  = (int*)take((size_t)NTOK*2*4);
  float* top_w = (float*)take((size_t)NTOK*2*4);
  int*  row_tok  = (int*)take((size_t)MAXR*4);
  float* row_w   = (float*)take((size_t)MAXR*4);
  int*  row_slot = (int*)take((size_t)MAXR*4);
  bf16* Xg     = (bf16*)take((size_t)MAXR*DIM*2);
  bf16* h13buf = (bf16*)take((size_t)MAXR*2*NF*2);    // [r][4096]
  bf16* hbuf   = (bf16*)take((size_t)MAXR*NF*2);
  // region A overlays Xg+h13buf head (50MB window); all dead before Xg/h13buf written
  char* ra = (char*)Xg;
  bf16* xn1 = (bf16*)ra;       ra += (size_t)NTOK*DIM*2;
  bf16* qkv = (bf16*)ra;       ra += (size_t)NTOK*1536*2;
  bf16* qr  = (bf16*)ra;       ra += (size_t)NTOK*DIM*2;
  bf16* krp = (bf16*)ra;       ra += (size_t)NTOK*NKV*HDIM*2; // 1MB
  bf16* vrp = (bf16*)ra;       ra += (size_t)NTOK*NKV*HDIM*2;
  bf16* vTp = (bf16*)ra;       ra += (size_t)NTOK*NKV*HDIM*2; // [B*KV][HD][S]
  bf16* attn_out = (bf16*)ra;  ra += (size_t)NTOK*DIM*2;
  float* ybuf = (float*)h13buf; // [2][NTOK][DIM] fp32 (16MB <= 40MB), h13buf dead by then

  // 0) zero counters
  k_zero_i32<<<dim3(1), dim3(256), 0, stream>>>(cnt, 16);
  // 1) weight transposes (fp32 -> bf16, B^T layout)
  k_transpose<<<dim3(32,32,1), dim3(32,8), 0, stream>>>(wq, wqkvT, 1024, 1024, (size_t)1024*1024, (size_t)1024*1024);
  k_transpose<<<dim3(8,32,1),  dim3(32,8), 0, stream>>>(wk, wqkvT + (size_t)1024*1024, 1024, 256, (size_t)1024*256, (size_t)1024*256);
  k_transpose<<<dim3(8,32,1),  dim3(32,8), 0, stream>>>(wv, wqkvT + (size_t)1280*1024, 1024, 256, (size_t)1024*256, (size_t)1024*256);
  k_transpose<<<dim3(32,32,1), dim3(32,8), 0, stream>>>(wo, woT, 1024, 1024, (size_t)1024*1024, (size_t)1024*1024);
  k_transpose<<<dim3(NF/32, DIM/32, NE), dim3(32,8), 0, stream>>>(w1, w13T, DIM, NF, (size_t)DIM*NF, (size_t)2*NF*DIM);
  k_transpose<<<dim3(NF/32, DIM/32, NE), dim3(32,8), 0, stream>>>(w3, w13T + (size_t)NF*DIM, DIM, NF, (size_t)DIM*NF, (size_t)2*NF*DIM);
  k_transpose<<<dim3(DIM/32, NF/32, NE), dim3(32,8), 0, stream>>>(w2, w2T, NF, DIM, (size_t)NF*DIM, (size_t)NF*DIM);
  // 2) ln1
  k_rmsnorm<<<dim3(NTOK), dim3(256), 0, stream>>>(hidden, ln1, xn1);
  // 3) qkv projection (BM=64 for fill)
  k_gemm<0,64><<<dim3(1536/BN, NTOK/64), dim3(256), 0, stream>>>(xn1, wqkvT, qkv, nullptr, nullptr, nullptr, nullptr, nullptr, nullptr, 1536, 1024);
  // 4) rope + reshape
  k_rope<<<dim3(NTOK), dim3(64), 0, stream>>>(qkv, pos, qr, krp, vrp);
  // 4b) V transpose -> [d][s]
  k_tbf<<<dim3(HDIM/32, SEQ/32, 2*NKV), dim3(32,8), 0, stream>>>(vrp, vTp, SEQ, HDIM);
  // 5) attention (MFMA flash)
  k_attn_mfma<<<dim3(SEQ/16, NH, 2), dim3(64), 0, stream>>>(qr, krp, vTp, attn_out);
  // 6) o-proj + residual -> h1 (fp32, BM=64)
  k_gemm<1,64><<<dim3(DIM/BN, NTOK/64), dim3(256), 0, stream>>>(attn_out, woT, nullptr, h1, hidden, nullptr, nullptr, nullptr, nullptr, DIM, 1024);
  // 7) fused ln2-rmsnorm + router (writes xn2 + gate_scores)
  k_router<<<dim3(NTOK), dim3(64), 0, stream>>>(h1, ln2, gw, out2, xn2, top_e, top_w, cnt);
  // 8) segment offsets + tile map
  k_offsets<<<dim3(1), dim3(256), 0, stream>>>(cnt, seg_off, tile_expert, row_tok);
  // 9) scatter pairs
  k_scatter<<<dim3(NTOK/256), dim3(256), 0, stream>>>(top_e, top_w, seg_off, cnt2, row_tok, row_w, row_slot);
  // 10) gather rows
  k_gather<<<dim3(MAXR), dim3(256), 0, stream>>>(row_tok, xn2, Xg);
  // 11) fused expert GEMM1 (w1|w3 stacked, N=4096, BM=128)
  k_gemm<2,128><<<dim3(2*NF/BN, MAXR/128), dim3(256), 0, stream>>>(Xg, w13T, h13buf, nullptr, nullptr, tile_expert, nullptr, nullptr, nullptr, 2*NF, DIM);
  // 12) swiglu from fused halves
  k_silumul<<<dim3((unsigned)((size_t)MAXR*NF/4/256)), dim3(256), 0, stream>>>(h13buf, hbuf);
  // 13) expert GEMM2 -> ybuf (weighted, scattered; BM=64 for fill)
  k_gemm<3,64><<<dim3(DIM/BN, MAXR/64), dim3(256), 0, stream>>>(hbuf, w2T, nullptr, ybuf, nullptr, tile_expert, row_tok, row_w, row_slot, DIM, NF);
  // 14) final residual add
  k_final<<<dim3(NTOK*DIM/4/256), dim3(256), 0, stream>>>(h1, ybuf, out1);
}